// Round 24
// baseline (132.730 us; speedup 1.0000x reference)
//
#include <hip/hip_runtime.h>
#include <hip/hip_bf16.h>

#define B_ 4
#define T_ 512
#define N_ 16
#define D_ 256
#define H_ 8
#define DK_ 32
#define NT_ (N_ * T_)
#define CTS_ 6
#define CN_ 4
#define CE_ 3
#define TSE_ 192
#define AUXE_ 64
#define SPLIT_ 8
#define KWORDS_ (NT_ / 64)   // 128 mask words per row

// Q pre-scale: (1/sqrt(32)) * log2(e) -> scores in exp2 domain, raw v_exp_f32
#define QSCALE_ 0.2550689747f

// padded LDS strides (elements): stride/2 dwords ≡ 6 mod 32 -> conflict-free b128
#define HTS_S 204
#define HAUX_S 76
#define HED_S 268
#define SK_S 268

typedef unsigned long long ull;
typedef unsigned int uint;
typedef __bf16 bf16x8 __attribute__((ext_vector_type(8)));
typedef float f32x4 __attribute__((ext_vector_type(4)));
typedef float f32x16 __attribute__((ext_vector_type(16)));

// ---- fused prep: pe table (blk<512) | maskbits (512..2559) | wprep (2560..4063)
__global__ __launch_bounds__(256) void prep_kernel(
    const int* __restrict__ mask, ull* __restrict__ bitsT, float* __restrict__ pe,
    const float* __restrict__ W_ts1, const float* __restrict__ W_a1,
    const float* __restrict__ W_e1, const float* __restrict__ W_ts2,
    const float* __restrict__ W_a2, const float* __restrict__ W_e2,
    const float* __restrict__ Wk, const float* __restrict__ Wv,
    const float* __restrict__ Wq, const float* __restrict__ Wo,
    __bf16* __restrict__ ts1P, __bf16* __restrict__ a1P, __bf16* __restrict__ e1P,
    __bf16* __restrict__ ts2T, __bf16* __restrict__ a2T, __bf16* __restrict__ e2T,
    __bf16* __restrict__ WkT, __bf16* __restrict__ WvT,
    __bf16* __restrict__ WqT, __bf16* __restrict__ WoT) {
    int blk = blockIdx.x;
    int tid = threadIdx.x;
    if (blk < 512) {
        int t = blk, d = tid;
        int j = d >> 1;
        float div = expf((float)(2 * j) * (-9.210340371976184f / 256.0f));
        float a = (float)t * div;
        pe[t * D_ + d] = (d & 1) ? cosf(a) : sinf(a);
        return;
    }
    if (blk < 2560) {
        int row = blk - 512;
        int b = row >> 9, t = row & (T_ - 1);
        const int* mrow = mask + (size_t)row * NT_;
        int lane = tid & 63, wave = tid >> 6;
        for (int it = 0; it < NT_ / 256; ++it) {
            int k = it * 256 + wave * 64 + lane;
            ull bal = __ballot(mrow[k] != 0);
            if (lane == 0) bitsT[((size_t)b * KWORDS_ + (k >> 6)) * T_ + t] = bal;
        }
        return;
    }
    int i = (blk - 2560) * 256 + tid;
    if (i < 6144) { int col = i >> 5, k = i & 31;
        ts1P[i] = (__bf16)(k < 6 ? W_ts1[k * TSE_ + col] : 0.f); return; }
    i -= 6144;
    if (i < 2048) { int col = i >> 5, k = i & 31;
        a1P[i] = (__bf16)((k >= 6 && k < 10) ? W_a1[(k - 6) * AUXE_ + col] : 0.f); return; }
    i -= 2048;
    if (i < 8192) { int col = i >> 5, k = i & 31;
        e1P[i] = (__bf16)((k >= 10 && k < 13) ? W_e1[(k - 10) * D_ + col] : 0.f); return; }
    i -= 8192;
    if (i < 36864) {  // ts2: COLS=192, KS=6
        int tile = i >> 9, lr = (i >> 5) & 15, kk = i & 31;
        int ct = tile / 6, ks = tile % 6;
        ts2T[i] = (__bf16)W_ts2[(ks * 32 + kk) * TSE_ + ct * 16 + lr]; return; }
    i -= 36864;
    if (i < 4096) {   // a2: COLS=64, KS=2
        int tile = i >> 9, lr = (i >> 5) & 15, kk = i & 31;
        int ct = tile / 2, ks = tile % 2;
        a2T[i] = (__bf16)W_a2[(ks * 32 + kk) * AUXE_ + ct * 16 + lr]; return; }
    i -= 4096;
    if (i < 65536) {  // e2: COLS=256, KS=8
        int tile = i >> 9, lr = (i >> 5) & 15, kk = i & 31;
        int ct = tile >> 3, ks = tile & 7;
        e2T[i] = (__bf16)W_e2[(ks * 32 + kk) * D_ + ct * 16 + lr]; return; }
    i -= 65536;
    if (i < 65536) {  // Wk
        int tile = i >> 9, lr = (i >> 5) & 15, kk = i & 31;
        int ct = tile >> 3, ks = tile & 7;
        WkT[i] = (__bf16)Wk[(ks * 32 + kk) * D_ + ct * 16 + lr]; return; }
    i -= 65536;
    if (i < 65536) {  // Wv
        int tile = i >> 9, lr = (i >> 5) & 15, kk = i & 31;
        int ct = tile >> 3, ks = tile & 7;
        WvT[i] = (__bf16)Wv[(ks * 32 + kk) * D_ + ct * 16 + lr]; return; }
    i -= 65536;
    if (i < 65536) {  // Wq (QSCALE pre-folded)
        int tile = i >> 9, lr = (i >> 5) & 15, kk = i & 31;
        int ct = tile >> 3, ks = tile & 7;
        WqT[i] = (__bf16)(Wq[(ks * 32 + kk) * D_ + ct * 16 + lr] * QSCALE_); return; }
    i -= 65536;
    {                 // Wo
        int tile = i >> 9, lr = (i >> 5) & 15, kk = i & 31;
        int ct = tile >> 3, ks = tile & 7;
        WoT[i] = (__bf16)Wo[(ks * 32 + kk) * D_ + ct * 16 + lr]; }
}

// --- fused kv chain (blk<1024) + q LN/proj (blk 1024..1087)
// 512 threads / 8 waves: each wave owns a 32-col strip (2 fragment tiles).
// Same LDS + per-block work as the 256-thread version -> intensity preserved,
// waves/SIMD doubles 4->8 (LDS-limited 4 blocks/CU x 8 waves = full occupancy).
__global__ __launch_bounds__(512, 8) void kvq_mfma_kernel(
    const float* __restrict__ md, const float* __restrict__ na, const float* __restrict__ ea,
    const __bf16* __restrict__ ts1P, const __bf16* __restrict__ a1P,
    const __bf16* __restrict__ e1P,
    const float* __restrict__ b_ts1, const float* __restrict__ b_a1,
    const float* __restrict__ b_e1,
    const __bf16* __restrict__ ts2T, const __bf16* __restrict__ a2T,
    const __bf16* __restrict__ e2T,
    const float* __restrict__ b_ts2, const float* __restrict__ b_a2,
    const float* __restrict__ b_e2,
    const __bf16* __restrict__ WkT, const float* __restrict__ bk,
    const __bf16* __restrict__ WvT, const float* __restrict__ bv,
    const float* __restrict__ pe, __bf16* __restrict__ Kb, __bf16* __restrict__ Vf,
    const float* __restrict__ x, const __bf16* __restrict__ WqT,
    const float* __restrict__ bq, const float* __restrict__ ln_g,
    const float* __restrict__ ln_b, __bf16* __restrict__ Qb) {
    int blk = blockIdx.x;
    int tid = threadIdx.x, lane = tid & 63;
    int wq = tid >> 6;             // wave 0..7 = 32-col strip
    int lr = lane & 15, lg = lane >> 4;

    // LDS union: kv {sA[1280] | sU[17536]} ; q {s_xn[8576]}
    __shared__ __bf16 sbuf[18816];

    int foff = lr * 32 + lg * 8;
    int crow0 = lg * 4;
    f32x4 z4 = {0.f, 0.f, 0.f, 0.f};

    if (blk >= 1024) {
        // ================= q path: x+pe, row-parallel LN, MFMA Q proj =======
        int qblk = blk - 1024;
        int t0 = (qblk & 15) * 32;
        int b = qblk >> 4;
        __bf16* s_xn = sbuf;

        {
            int row = tid >> 4, sub = tid & 15;   // 16 threads/row
            size_t roff = ((size_t)b * T_ + t0 + row) * D_;
            const float* pr = pe + (t0 + row) * D_;
            f32x4 vv[4];
            float s1 = 0.f, s2 = 0.f;
#pragma unroll
            for (int q4 = 0; q4 < 4; ++q4) {
                int c = q4 * 64 + sub * 4;
                f32x4 xv = *(const f32x4*)(x + roff + c);
                f32x4 pv = *(const f32x4*)(pr + c);
                f32x4 t4;
#pragma unroll
                for (int j = 0; j < 4; ++j) {
                    t4[j] = xv[j] + pv[j];
                    s1 += t4[j];
                    s2 += t4[j] * t4[j];
                }
                vv[q4] = t4;
            }
#pragma unroll
            for (int o = 1; o <= 8; o <<= 1) {
                s1 += __shfl_xor(s1, o, 64);
                s2 += __shfl_xor(s2, o, 64);
            }
            float mu = s1 * (1.f / D_);
            float var = s2 * (1.f / D_) - mu * mu;
            float rs = rsqrtf(var + 1e-6f);
#pragma unroll
            for (int q4 = 0; q4 < 4; ++q4) {
                int c = q4 * 64 + sub * 4;
                f32x4 g4 = *(const f32x4*)(ln_g + c);
                f32x4 b4 = *(const f32x4*)(ln_b + c);
#pragma unroll
                for (int j = 0; j < 4; ++j)
                    s_xn[row * SK_S + c + j] = (__bf16)((vv[q4][j] - mu) * rs * g4[j] + b4[j]);
            }
        }
        __syncthreads();

        f32x4 qa[2][2];
#pragma unroll
        for (int i = 0; i < 2; ++i) { qa[0][i] = z4; qa[1][i] = z4; }
        const __bf16* qbse = WqT + (size_t)(wq * 2) * 8 * 512 + foff;
#pragma unroll
        for (int ks = 0; ks < 8; ++ks) {
            bf16x8 af0 = *(const bf16x8*)(s_xn + lr * SK_S + ks * 32 + lg * 8);
            bf16x8 af1 = *(const bf16x8*)(s_xn + (16 + lr) * SK_S + ks * 32 + lg * 8);
#pragma unroll
            for (int i = 0; i < 2; ++i) {
                bf16x8 b8 = *(const bf16x8*)(qbse + i * 4096 + ks * 512);
                qa[0][i] = __builtin_amdgcn_mfma_f32_16x16x32_bf16(af0, b8, qa[0][i], 0, 0, 0);
                qa[1][i] = __builtin_amdgcn_mfma_f32_16x16x32_bf16(af1, b8, qa[1][i], 0, 0, 0);
            }
        }
#pragma unroll
        for (int i = 0; i < 2; ++i) {
            int gcol = wq * 32 + i * 16 + lr;
            float bias = bq[gcol] * QSCALE_;
#pragma unroll
            for (int rf = 0; rf < 2; ++rf)
#pragma unroll
                for (int r = 0; r < 4; ++r)
                    Qb[((size_t)b * T_ + t0 + rf * 16 + crow0 + r) * D_ + gcol] =
                        (__bf16)(qa[rf][i][r] + bias);
        }
        return;
    }

    // ================= kv path =================
    int t0 = (blk & 15) * 32;
    int n = (blk >> 4) & 15;
    int b = blk >> 8;
    __bf16* sA = sbuf;                   // [32*40]
    __bf16* sU = sbuf + 1280;
    __bf16* hts = sU;                    // [32][204]
    __bf16* haux = sU + 6528;            // [32][76]
    __bf16* hedge = sU + 8960;           // [32][268]
    __bf16* skey = sU;                   // [32][268]
    __bf16* sval = sU + 8576;            // [32][268]

    for (int i = tid; i < 32 * 40; i += 512) sA[i] = (__bf16)0.f;
    __syncthreads();
    {
        int t = tid & 31, c0 = tid >> 5;     // c0 0..15
        size_t bn = (size_t)b * N_ + n;
        if (c0 < 13) {
            float v;
            if (c0 < 6) v = md[(bn * CTS_ + c0) * T_ + t0 + t];
            else if (c0 < 10) v = na[(bn * CN_ + (c0 - 6)) * T_ + t0 + t];
            else v = ea[(bn * CE_ + (c0 - 10)) * T_ + t0 + t];
            sA[t * 40 + c0] = (__bf16)v;
        }
    }
    __syncthreads();

    bf16x8 a1f0 = *(const bf16x8*)(sA + lr * 40 + lg * 8);
    bf16x8 a1f1 = *(const bf16x8*)(sA + (16 + lr) * 40 + lg * 8);

    // ---- phase 2: first layers (K=32); waves 0-5 -> ts (12 tiles), 6-7 -> aux
    {
        bool isTs = (wq < 6);
#pragma unroll
        for (int i = 0; i < 2; ++i) {
            int ctn = wq * 2 + i;
            const __bf16* src = isTs ? (ts1P + ctn * 512) : (a1P + (ctn - 12) * 512);
            bf16x8 bf = *(const bf16x8*)(src + foff);
            f32x4 c0 = __builtin_amdgcn_mfma_f32_16x16x32_bf16(a1f0, bf, z4, 0, 0, 0);
            f32x4 c1 = __builtin_amdgcn_mfma_f32_16x16x32_bf16(a1f1, bf, z4, 0, 0, 0);
            if (isTs) {
                int gcol = ctn * 16 + lr;
                float bias = b_ts1[gcol];
#pragma unroll
                for (int r = 0; r < 4; ++r) {
                    hts[(crow0 + r) * HTS_S + gcol] = (__bf16)fmaxf(c0[r] + bias, 0.f);
                    hts[(16 + crow0 + r) * HTS_S + gcol] = (__bf16)fmaxf(c1[r] + bias, 0.f);
                }
            } else {
                int acol = (ctn - 12) * 16 + lr;
                float bias = b_a1[acol];
#pragma unroll
                for (int r = 0; r < 4; ++r) {
                    haux[(crow0 + r) * HAUX_S + acol] = (__bf16)fmaxf(c0[r] + bias, 0.f);
                    haux[(16 + crow0 + r) * HAUX_S + acol] = (__bf16)fmaxf(c1[r] + bias, 0.f);
                }
            }
        }
#pragma unroll
        for (int i = 0; i < 2; ++i) {
            int cte = wq * 2 + i;
            bf16x8 bf = *(const bf16x8*)(e1P + cte * 512 + foff);
            f32x4 c0 = __builtin_amdgcn_mfma_f32_16x16x32_bf16(a1f0, bf, z4, 0, 0, 0);
            f32x4 c1 = __builtin_amdgcn_mfma_f32_16x16x32_bf16(a1f1, bf, z4, 0, 0, 0);
            int gcol = cte * 16 + lr;
            float bias = b_e1[gcol];
#pragma unroll
            for (int r = 0; r < 4; ++r) {
                hedge[(crow0 + r) * HED_S + gcol] = (__bf16)fmaxf(c0[r] + bias, 0.f);
                hedge[(16 + crow0 + r) * HED_S + gcol] = (__bf16)fmaxf(c1[r] + bias, 0.f);
            }
        }
    }
    __syncthreads();

    // ---- phase 3a: edge second layer
    f32x4 eacc[2][2];
#pragma unroll
    for (int i = 0; i < 2; ++i) { eacc[0][i] = z4; eacc[1][i] = z4; }
    {
        const __bf16* ebase = e2T + (size_t)(wq * 2) * 8 * 512 + foff;
        bf16x8 bcur[2];
#pragma unroll
        for (int i = 0; i < 2; ++i) bcur[i] = *(const bf16x8*)(ebase + i * 4096);
#pragma unroll 1
        for (int ks = 0; ks < 8; ++ks) {
            bf16x8 bnext[2];
            if (ks < 7) {
#pragma unroll
                for (int i = 0; i < 2; ++i)
                    bnext[i] = *(const bf16x8*)(ebase + i * 4096 + (ks + 1) * 512);
            }
            __builtin_amdgcn_sched_barrier(0);
            bf16x8 af0 = *(const bf16x8*)(hedge + lr * HED_S + ks * 32 + lg * 8);
            bf16x8 af1 = *(const bf16x8*)(hedge + (16 + lr) * HED_S + ks * 32 + lg * 8);
#pragma unroll
            for (int i = 0; i < 2; ++i) {
                eacc[0][i] = __builtin_amdgcn_mfma_f32_16x16x32_bf16(af0, bcur[i], eacc[0][i], 0, 0, 0);
                eacc[1][i] = __builtin_amdgcn_mfma_f32_16x16x32_bf16(af1, bcur[i], eacc[1][i], 0, 0, 0);
            }
            if (ks < 7) {
#pragma unroll
                for (int i = 0; i < 2; ++i) bcur[i] = bnext[i];
            }
        }
    }

    // ---- phase 3b: nbr second layer; waves 0-5 -> ts2, 6-7 -> aux2
    f32x4 nacc[2][2];
#pragma unroll
    for (int i = 0; i < 2; ++i) { nacc[0][i] = z4; nacc[1][i] = z4; }
    if (wq < 6) {
        const __bf16* nbase = ts2T + (size_t)(wq * 2) * 6 * 512 + foff;
        bf16x8 bcur[2];
#pragma unroll
        for (int i = 0; i < 2; ++i) bcur[i] = *(const bf16x8*)(nbase + i * 3072);
#pragma unroll 1
        for (int ks = 0; ks < 6; ++ks) {
            bf16x8 bnext[2];
            if (ks < 5) {
#pragma unroll
                for (int i = 0; i < 2; ++i)
                    bnext[i] = *(const bf16x8*)(nbase + i * 3072 + (ks + 1) * 512);
            }
            __builtin_amdgcn_sched_barrier(0);
            bf16x8 af0 = *(const bf16x8*)(hts + lr * HTS_S + ks * 32 + lg * 8);
            bf16x8 af1 = *(const bf16x8*)(hts + (16 + lr) * HTS_S + ks * 32 + lg * 8);
#pragma unroll
            for (int i = 0; i < 2; ++i) {
                nacc[0][i] = __builtin_amdgcn_mfma_f32_16x16x32_bf16(af0, bcur[i], nacc[0][i], 0, 0, 0);
                nacc[1][i] = __builtin_amdgcn_mfma_f32_16x16x32_bf16(af1, bcur[i], nacc[1][i], 0, 0, 0);
            }
            if (ks < 5) {
#pragma unroll
                for (int i = 0; i < 2; ++i) bcur[i] = bnext[i];
            }
        }
    } else {
#pragma unroll
        for (int ks = 0; ks < 2; ++ks) {
            bf16x8 af0 = *(const bf16x8*)(haux + lr * HAUX_S + ks * 32 + lg * 8);
            bf16x8 af1 = *(const bf16x8*)(haux + (16 + lr) * HAUX_S + ks * 32 + lg * 8);
#pragma unroll
            for (int i = 0; i < 2; ++i) {
                int ct = (wq - 6) * 2 + i;
                bf16x8 bf = *(const bf16x8*)(a2T + (ct * 2 + ks) * 512 + foff);
                nacc[0][i] = __builtin_amdgcn_mfma_f32_16x16x32_bf16(af0, bf, nacc[0][i], 0, 0, 0);
                nacc[1][i] = __builtin_amdgcn_mfma_f32_16x16x32_bf16(af1, bf, nacc[1][i], 0, 0, 0);
            }
        }
    }
    __syncthreads();

    // ---- phase 3c: key/val assembly
#pragma unroll
    for (int i = 0; i < 2; ++i) {
        int gcol = wq * 32 + i * 16 + lr;
        float nb_bias = (wq < 6) ? b_ts2[gcol] : b_a2[gcol - 192];
        float ed_bias = b_e2[gcol];
#pragma unroll
        for (int rf = 0; rf < 2; ++rf)
#pragma unroll
            for (int r = 0; r < 4; ++r) {
                int row = rf * 16 + crow0 + r;
                float p = pe[(t0 + row) * D_ + gcol];
                float nb = nacc[rf][i][r] + nb_bias;
                float ed = eacc[rf][i][r] + ed_bias;
                skey[row * SK_S + gcol] = (__bf16)(nb * ed + p);
                sval[row * SK_S + gcol] = (__bf16)(nb + p);
            }
    }
    __syncthreads();

    size_t key0 = (size_t)n * T_ + t0;

    // ---- phase 4a: K projection
    {
        const __bf16* kbse = WkT + (size_t)(wq * 2) * 8 * 512 + foff;
        f32x4 ka[2][2];
#pragma unroll
        for (int i = 0; i < 2; ++i) { ka[0][i] = z4; ka[1][i] = z4; }
        bf16x8 bcur[2];
#pragma unroll
        for (int i = 0; i < 2; ++i) bcur[i] = *(const bf16x8*)(kbse + i * 4096);
#pragma unroll 1
        for (int ks = 0; ks < 8; ++ks) {
            bf16x8 bnext[2];
            if (ks < 7) {
#pragma unroll
                for (int i = 0; i < 2; ++i)
                    bnext[i] = *(const bf16x8*)(kbse + i * 4096 + (ks + 1) * 512);
            }
            __builtin_amdgcn_sched_barrier(0);
            bf16x8 af0 = *(const bf16x8*)(skey + lr * SK_S + ks * 32 + lg * 8);
            bf16x8 af1 = *(const bf16x8*)(skey + (16 + lr) * SK_S + ks * 32 + lg * 8);
#pragma unroll
            for (int i = 0; i < 2; ++i) {
                ka[0][i] = __builtin_amdgcn_mfma_f32_16x16x32_bf16(af0, bcur[i], ka[0][i], 0, 0, 0);
                ka[1][i] = __builtin_amdgcn_mfma_f32_16x16x32_bf16(af1, bcur[i], ka[1][i], 0, 0, 0);
            }
            if (ks < 7) {
#pragma unroll
                for (int i = 0; i < 2; ++i) bcur[i] = bnext[i];
            }
        }
#pragma unroll
        for (int i = 0; i < 2; ++i) {
            int gcol = wq * 32 + i * 16 + lr;
            float kbias = bk[gcol];
            int h = gcol >> 5, dd = gcol & 31;
            size_t bh = (size_t)b * H_ + h;
#pragma unroll
            for (int rf = 0; rf < 2; ++rf) {
                int crow = rf * 16 + crow0;
#pragma unroll
                for (int r = 0; r < 4; ++r)
                    Kb[(bh * NT_ + key0 + crow + r) * DK_ + dd] = (__bf16)(ka[rf][i][r] + kbias);
            }
        }
    }

    // ---- phase 4b: V projection
    {
        const __bf16* vbse = WvT + (size_t)(wq * 2) * 8 * 512 + foff;
        f32x4 va[2][2];
#pragma unroll
        for (int i = 0; i < 2; ++i) { va[0][i] = z4; va[1][i] = z4; }
        bf16x8 bcur[2];
#pragma unroll
        for (int i = 0; i < 2; ++i) bcur[i] = *(const bf16x8*)(vbse + i * 4096);
#pragma unroll 1
        for (int ks = 0; ks < 8; ++ks) {
            bf16x8 bnext[2];
            if (ks < 7) {
#pragma unroll
                for (int i = 0; i < 2; ++i)
                    bnext[i] = *(const bf16x8*)(vbse + i * 4096 + (ks + 1) * 512);
            }
            __builtin_amdgcn_sched_barrier(0);
            bf16x8 af0 = *(const bf16x8*)(sval + lr * SK_S + ks * 32 + lg * 8);
            bf16x8 af1 = *(const bf16x8*)(sval + (16 + lr) * SK_S + ks * 32 + lg * 8);
#pragma unroll
            for (int i = 0; i < 2; ++i) {
                va[0][i] = __builtin_amdgcn_mfma_f32_16x16x32_bf16(af0, bcur[i], va[0][i], 0, 0, 0);
                va[1][i] = __builtin_amdgcn_mfma_f32_16x16x32_bf16(af1, bcur[i], va[1][i], 0, 0, 0);
            }
            if (ks < 7) {
#pragma unroll
                for (int i = 0; i < 2; ++i) bcur[i] = bnext[i];
            }
        }
#pragma unroll
        for (int i = 0; i < 2; ++i) {
            int gcol = wq * 32 + i * 16 + lr;
            float vbias = bv[gcol];
            int h = gcol >> 5, dd = gcol & 31;
            size_t bh = (size_t)b * H_ + h;
#pragma unroll
            for (int rf = 0; rf < 2; ++rf) {
                int crow = rf * 16 + crow0;
                __bf16 tmp[4];
#pragma unroll
                for (int r = 0; r < 4; ++r) tmp[r] = (__bf16)(va[rf][i][r] + vbias);
                size_t kg = key0 + crow;
                int within = (int)(kg & 63);
                int vks = within >> 4, vl5 = (within >> 3) & 1, j0 = within & 7;
                size_t tile = kg >> 6;
                size_t vaddr = ((bh * (NT_ / 64) + tile) * 4 + vks) * 512 +
                               (size_t)(vl5 * 32 + dd) * 8 + j0;
                *(ushort4*)(Vf + vaddr) = *(ushort4*)tmp;
            }
        }
    }
}

// ------- 32x32 MFMA attention: raw v_exp (exp2 domain), sbfe mask, ones-MFMA l
// Opart stored bf16 (unnormalized partial O; bf16 rel-err ~0.4% << threshold)
__global__ __launch_bounds__(256, 4) void attn_mfma_kernel(
    const __bf16* __restrict__ Qb, const __bf16* __restrict__ Kb,
    const __bf16* __restrict__ Vf, const ull* __restrict__ bitsT,
    __bf16* __restrict__ Opart, float* __restrict__ Lpart) {
    int blk = blockIdx.x;
    int kh = blk & (SPLIT_ - 1);
    int qt = (blk >> 3) & 3;
    int h = (blk >> 5) & 7;
    int b = blk >> 8;
    int tid = threadIdx.x, lane = tid & 63, w = tid >> 6;
    int lq = lane & 31, l5 = lane >> 5;

    const size_t bh = (size_t)b * H_ + h;
    const int TILES = KWORDS_ / SPLIT_;   // 16

    int qglob = qt * 128 + w * 32 + lq;
    const __bf16* qbase = Qb + ((size_t)b * T_ + qglob) * D_ + h * DK_ + l5 * 8;
    bf16x8 qf0 = *(const bf16x8*)(qbase);
    bf16x8 qf1 = *(const bf16x8*)(qbase + 16);

    const __bf16* kp = Kb + bh * NT_ * DK_ + (size_t)(kh * TILES) * 64 * DK_;
    const __bf16* vp = Vf + (bh * (NT_ / 64) + (size_t)(kh * TILES)) * 2048;
    const ull* mp = bitsT + (size_t)b * KWORDS_ * T_ + (size_t)(kh * TILES) * T_ + qglob;

    int k00 = lq * DK_ + l5 * 8;
    int k01 = k00 + 16;
    int k10 = (32 + lq) * DK_ + l5 * 8;
    int k11 = k10 + 16;
    int shamt = 4 * l5;

    f32x16 acc, acc_l, zv;
#pragma unroll
    for (int i = 0; i < 16; ++i) { acc[i] = 0.f; acc_l[i] = 0.f; zv[i] = 0.f; }
    union { uint u[4]; bf16x8 v; } onesf;
    onesf.u[0] = 0x3F803F80u; onesf.u[1] = 0x3F803F80u;
    onesf.u[2] = 0x3F803F80u; onesf.u[3] = 0x3F803F80u;

    bf16x8 kc0 = *(const bf16x8*)(kp + k00);
    bf16x8 kc1 = *(const bf16x8*)(kp + k01);
    bf16x8 kc2 = *(const bf16x8*)(kp + k10);
    bf16x8 kc3 = *(const bf16x8*)(kp + k11);
    ull mw = *mp;

#pragma unroll 1
    for (int kt = 0; kt < TILES; ++kt) {
        bf16x8 vc0 = *(const bf16x8*)(vp + 0 * 512 + lane * 8);
        bf16x8 vc1 = *(const bf16x8*)(vp + 1 * 512 + lane * 8);
        bf16x8 vc2 = *(const bf16x8*)(vp + 2 * 512 + lane * 8);
        bf16x8 vc3 = *(const bf16x8*)(vp + 3 * 512 + lane * 8);
        bf16x8 kn0, kn1, kn2, kn3;
        ull mn = 0;
        if (kt + 1 < TILES) {
            kn0 = *(const bf16x8*)(kp + 2048 + k00);
            kn1 = *(const bf16x8*)(kp + 2048 + k01);
            kn2 = *(const bf16x8*)(kp + 2048 + k10);
            kn3 = *(const bf16x8*)(kp + 2048 + k11);
            mn = mp[T_];
        }
        __builtin_amdgcn_sched_barrier(0);

        ull sh = mw >> shamt;

#pragma unroll
        for (int s = 0; s < 2; ++s) {
            f32x16 sc = __builtin_amdgcn_mfma_f32_32x32x16_bf16(
                s ? kc2 : kc0, qf0, zv, 0, 0, 0);
            sc = __builtin_amdgcn_mfma_f32_32x32x16_bf16(
                s ? kc3 : kc1, qf1, sc, 0, 0, 0);

            uint ms = (uint)(sh >> (32 * s));
            float p[16];
#pragma unroll
            for (int r = 0; r < 16; ++r) {
                int pos = (r & 3) + 8 * (r >> 2);
                float e = __builtin_amdgcn_exp2f(sc[r]);                 // raw v_exp
                int mb = __builtin_amdgcn_sbfe((int)ms, (uint)pos, 1u);  // 0 or -1
                p[r] = __uint_as_float(__float_as_uint(e) & (uint)mb);
            }

#pragma unroll
            for (int h2 = 0; h2 < 2; ++h2) {
                uint w0, w1, w2, w3;
                asm("v_cvt_pk_bf16_f32 %0, %1, %2" : "=v"(w0) : "v"(p[8 * h2 + 0]), "v"(p[8 * h2 + 1]));
                asm("v_cvt_pk_bf16_f32 %0, %1, %2" : "=v"(w1) : "v"(p[8 * h2 + 2]), "v"(p[8 * h2 + 3]));
                asm("v_cvt_pk_bf16_f32 %0, %1, %2" : "=v"(w2) : "v"(p[8 * h2 + 4]), "v"(p[8 * h2 + 5]));
                asm("v_cvt_pk_bf16_f32 %0, %1, %2" : "=v"(w3) : "v"(p[8 * h2 + 6]), "v"(p[8 * h2 + 7]));
                asm volatile("v_permlane32_swap_b32 %0, %1" : "+v"(w0), "+v"(w2));
                asm volatile("v_permlane32_swap_b32 %0, %1" : "+v"(w1), "+v"(w3));
                union { uint u[4]; bf16x8 v; } pa;
                pa.u[0] = w0; pa.u[1] = w1; pa.u[2] = w2; pa.u[3] = w3;
                bf16x8 vfr = (s == 0) ? (h2 == 0 ? vc0 : vc1) : (h2 == 0 ? vc2 : vc3);
                acc = __builtin_amdgcn_mfma_f32_32x32x16_bf16(pa.v, vfr, acc, 0, 0, 0);
                acc_l = __builtin_amdgcn_mfma_f32_32x32x16_bf16(pa.v, onesf.v, acc_l, 0, 0, 0);
            }
        }

        kp += 2048;
        vp += 2048;
        mp += T_;
        if (kt + 1 < TILES) {
            kc0 = kn0; kc1 = kn1; kc2 = kn2; kc3 = kn3;
            mw = mn;
        }
    }

    size_t obase = (((size_t)kh * B_ + b) * H_ + h) * T_ + qt * 128 + w * 32;
#pragma unroll
    for (int r = 0; r < 16; ++r) {
        int q = (r & 3) + 8 * (r >> 2) + 4 * l5;
        Opart[(obase + q) * DK_ + lq] = (__bf16)acc[r];
    }
    if (lq == 0) {
#pragma unroll
        for (int r = 0; r < 16; ++r) {
            int q = (r & 3) + 8 * (r >> 2) + 4 * l5;
            Lpart[obase + q] = acc_l[r];
        }
    }
}

// ------ out = (x+pe) + (merge of bf16 Opart / f32 Lpart)@Wo + bo, grid 64
__global__ __launch_bounds__(256) void out_mfma_kernel(
    const __bf16* __restrict__ Opart, const float* __restrict__ Lpart,
    const float* __restrict__ x, const float* __restrict__ pe,
    const __bf16* __restrict__ WoT, const float* __restrict__ bo,
    float* __restrict__ out) {
    int blk = blockIdx.x;
    int t0 = (blk & 15) * 32;
    int b = blk >> 4;
    int tid = threadIdx.x, lane = tid & 63;
    int wq = tid >> 6, lr = lane & 15, lg = lane >> 4;

    __shared__ __bf16 sc_[32 * SK_S];
    __shared__ float sLinv[32 * 8];
    size_t ps = (size_t)B_ * H_ * T_;

    // phase A: 1/L per (row, head)
    {
        int row = tid >> 3, hh = tid & 7;
        size_t base = ((size_t)b * H_ + hh) * T_ + t0 + row;
        float L = 0.f;
#pragma unroll
        for (int s = 0; s < SPLIT_; ++s) L += Lpart[s * ps + base];
        sLinv[row * 8 + hh] = 1.0f / L;
    }
    __syncthreads();

    // phase B: merge bf16 Opart -> ctx bf16 in LDS
    for (int idx = tid; idx < 32 * 64; idx += 256) {
        int r = idx >> 6, g = idx & 63;
        int hh = g >> 3, d4 = (g & 7) * 4;
        size_t base = (((size_t)b * H_ + hh) * T_ + t0 + r) * DK_ + d4;
        float o0 = 0.f, o1 = 0.f, o2 = 0.f, o3 = 0.f;
#pragma unroll
        for (int s = 0; s < SPLIT_; ++s) {
            union { ushort4 u; __bf16 h[4]; } cv;
            cv.u = *(const ushort4*)(Opart + s * ps * DK_ + base);
            o0 += (float)cv.h[0]; o1 += (float)cv.h[1];
            o2 += (float)cv.h[2]; o3 += (float)cv.h[3];
        }
        float li = sLinv[r * 8 + hh];
        int c = hh * 32 + d4;
        sc_[r * SK_S + c + 0] = (__bf16)(o0 * li);
        sc_[r * SK_S + c + 1] = (__bf16)(o1 * li);
        sc_[r * SK_S + c + 2] = (__bf16)(o2 * li);
        sc_[r * SK_S + c + 3] = (__bf16)(o3 * li);
    }
    __syncthreads();

    int foff = lr * 32 + lg * 8;
    int crow0 = lg * 4;
    f32x4 z4 = {0.f, 0.f, 0.f, 0.f};
    f32x4 oa[2][4];
#pragma unroll
    for (int i = 0; i < 4; ++i) { oa[0][i] = z4; oa[1][i] = z4; }
    const __bf16* obse = WoT + (size_t)(wq * 4) * 8 * 512 + foff;
#pragma unroll
    for (int ks = 0; ks < 8; ++ks) {
        bf16x8 af0 = *(const bf16x8*)(sc_ + lr * SK_S + ks * 32 + lg * 8);
        bf16x8 af1 = *(const bf16x8*)(sc_ + (16 + lr) * SK_S + ks * 32 + lg * 8);
#pragma unroll
        for (int i = 0; i < 4; ++i) {
            bf16x8 b8 = *(const bf16x8*)(obse + i * 4096 + ks * 512);
            oa[0][i] = __builtin_amdgcn_mfma_f32_16x16x32_bf16(af0, b8, oa[0][i], 0, 0, 0);
            oa[1][i] = __builtin_amdgcn_mfma_f32_16x16x32_bf16(af1, b8, oa[1][i], 0, 0, 0);
        }
    }
#pragma unroll
    for (int i = 0; i < 4; ++i) {
        int gcol = wq * 64 + i * 16 + lr;
        float bias = bo[gcol];
#pragma unroll
        for (int rf = 0; rf < 2; ++rf)
#pragma unroll
            for (int r = 0; r < 4; ++r) {
                int t = t0 + rf * 16 + crow0 + r;
                size_t off = ((size_t)b * T_ + t) * D_ + gcol;
                out[off] = x[off] + pe[t * D_ + gcol] + oa[rf][i][r] + bias;
            }
    }
}

// ---------------------------------------------------------------- launcher
extern "C" void kernel_launch(void* const* d_in, const int* in_sizes, int n_in,
                              void* d_out, int out_size, void* d_ws, size_t ws_size,
                              hipStream_t stream) {
    const float* x = (const float*)d_in[0];
    const float* md = (const float*)d_in[1];
    const float* na = (const float*)d_in[2];
    const float* ea = (const float*)d_in[3];
    const int* mask = (const int*)d_in[4];
    const float* W_ts1 = (const float*)d_in[5];
    const float* b_ts1 = (const float*)d_in[6];
    const float* W_ts2 = (const float*)d_in[7];
    const float* b_ts2 = (const float*)d_in[8];
    const float* W_a1 = (const float*)d_in[9];
    const float* b_a1 = (const float*)d_in[10];
    const float* W_a2 = (const float*)d_in[11];
    const float* b_a2 = (const float*)d_in[12];
    const float* W_e1 = (const float*)d_in[13];
    const float* b_e1 = (const float*)d_in[14];
    const float* W_e2 = (const float*)d_in[15];
    const float* b_e2 = (const float*)d_in[16];
    const float* Wq = (const float*)d_in[17];
    const float* bq = (const float*)d_in[18];
    const float* Wk = (const float*)d_in[19];
    const float* bk = (const float*)d_in[20];
    const float* Wv = (const float*)d_in[21];
    const float* bv = (const float*)d_in[22];
    const float* Wo = (const float*)d_in[23];
    const float* bo = (const float*)d_in[24];
    const float* ln_g = (const float*)d_in[25];
    const float* ln_b = (const float*)d_in[26];
    float* out = (float*)d_out;

    char* ws = (char*)d_ws;
    float* pe = (float*)ws;      ws += (size_t)T_ * D_ * 4;
    ull* bitsT = (ull*)ws;       ws += (size_t)B_ * KWORDS_ * T_ * 8;    // 2 MB
    __bf16* Kb = (__bf16*)ws;    ws += (size_t)B_ * H_ * NT_ * DK_ * 2;  // 16 MB
    __bf16* Vf = (__bf16*)ws;    ws += (size_t)B_ * H_ * NT_ * DK_ * 2;  // 16 MB
    __bf16* Qb = (__bf16*)ws;    ws += (size_t)B_ * T_ * D_ * 2;         // 1 MB
    __bf16* Opart = (__bf16*)ws; ws += (size_t)SPLIT_ * B_ * H_ * T_ * DK_ * 2;  // 8 MB
    float* Lpart = (float*)ws;   ws += (size_t)SPLIT_ * B_ * H_ * T_ * 4;
    // bf16 prepped weights
    __bf16* ts1P = (__bf16*)ws; ws += 6144 * 2;
    __bf16* a1P = (__bf16*)ws;  ws += 2048 * 2;
    __bf16* e1P = (__bf16*)ws;  ws += 8192 * 2;
    __bf16* ts2T = (__bf16*)ws; ws += 36864 * 2;
    __bf16* a2T = (__bf16*)ws;  ws += 4096 * 2;
    __bf16* e2T = (__bf16*)ws;  ws += 65536 * 2;
    __bf16* WkT = (__bf16*)ws;  ws += 65536 * 2;
    __bf16* WvT = (__bf16*)ws;  ws += 65536 * 2;
    __bf16* WqT = (__bf16*)ws;  ws += 65536 * 2;
    __bf16* WoT = (__bf16*)ws;  ws += 65536 * 2;

    prep_kernel<<<4064, 256, 0, stream>>>(mask, bitsT, pe,
                                          W_ts1, W_a1, W_e1, W_ts2, W_a2, W_e2,
                                          Wk, Wv, Wq, Wo,
                                          ts1P, a1P, e1P, ts2T, a2T, e2T,
                                          WkT, WvT, WqT, WoT);
    kvq_mfma_kernel<<<B_ * N_ * (T_ / 32) + B_ * (T_ / 32), 512, 0, stream>>>(
        md, na, ea, ts1P, a1P, e1P, b_ts1, b_a1, b_e1,
        ts2T, a2T, e2T, b_ts2, b_a2, b_e2, WkT, bk, WvT, bv, pe, Kb, Vf,
        x, WqT, bq, ln_g, ln_b, Qb);
    attn_mfma_kernel<<<B_ * H_ * (T_ / 128) * SPLIT_, 256, 0, stream>>>(
        Qb, Kb, Vf, bitsT, Opart, Lpart);
    out_mfma_kernel<<<B_ * (T_ / 32), 256, 0, stream>>>(Opart, Lpart, x, pe, WoT, bo, out);
}

// Round 25
// 109.040 us; speedup vs baseline: 1.2173x; 1.2173x over previous
//
#include <hip/hip_runtime.h>
#include <hip/hip_bf16.h>

#define B_ 4
#define T_ 512
#define N_ 16
#define D_ 256
#define H_ 8
#define DK_ 32
#define NT_ (N_ * T_)
#define CTS_ 6
#define CN_ 4
#define CE_ 3
#define TSE_ 192
#define AUXE_ 64
#define SPLIT_ 8
#define KWORDS_ (NT_ / 64)   // 128 mask words per row

// Q pre-scale: (1/sqrt(32)) * log2(e) -> scores in exp2 domain, raw v_exp_f32
#define QSCALE_ 0.2550689747f

// padded LDS strides (elements): stride/2 dwords ≡ 6 mod 32 -> conflict-free b128
#define HTS_S 204
#define HAUX_S 76
#define HED_S 268
#define SK_S 268

typedef unsigned long long ull;
typedef unsigned int uint;
typedef __bf16 bf16x8 __attribute__((ext_vector_type(8)));
typedef float f32x4 __attribute__((ext_vector_type(4)));
typedef float f32x16 __attribute__((ext_vector_type(16)));

// ---- fused prep: pe table (blk<512) | maskbits (512..2559) | wprep (2560..4063)
__global__ __launch_bounds__(256) void prep_kernel(
    const int* __restrict__ mask, ull* __restrict__ bitsT, float* __restrict__ pe,
    const float* __restrict__ W_ts1, const float* __restrict__ W_a1,
    const float* __restrict__ W_e1, const float* __restrict__ W_ts2,
    const float* __restrict__ W_a2, const float* __restrict__ W_e2,
    const float* __restrict__ Wk, const float* __restrict__ Wv,
    const float* __restrict__ Wq, const float* __restrict__ Wo,
    __bf16* __restrict__ ts1P, __bf16* __restrict__ a1P, __bf16* __restrict__ e1P,
    __bf16* __restrict__ ts2T, __bf16* __restrict__ a2T, __bf16* __restrict__ e2T,
    __bf16* __restrict__ WkT, __bf16* __restrict__ WvT,
    __bf16* __restrict__ WqT, __bf16* __restrict__ WoT) {
    int blk = blockIdx.x;
    int tid = threadIdx.x;
    if (blk < 512) {
        int t = blk, d = tid;
        int j = d >> 1;
        float div = expf((float)(2 * j) * (-9.210340371976184f / 256.0f));
        float a = (float)t * div;
        pe[t * D_ + d] = (d & 1) ? cosf(a) : sinf(a);
        return;
    }
    if (blk < 2560) {
        int row = blk - 512;
        int b = row >> 9, t = row & (T_ - 1);
        const int* mrow = mask + (size_t)row * NT_;
        int lane = tid & 63, wave = tid >> 6;
        for (int it = 0; it < NT_ / 256; ++it) {
            int k = it * 256 + wave * 64 + lane;
            ull bal = __ballot(mrow[k] != 0);
            if (lane == 0) bitsT[((size_t)b * KWORDS_ + (k >> 6)) * T_ + t] = bal;
        }
        return;
    }
    int i = (blk - 2560) * 256 + tid;
    if (i < 6144) { int col = i >> 5, k = i & 31;
        ts1P[i] = (__bf16)(k < 6 ? W_ts1[k * TSE_ + col] : 0.f); return; }
    i -= 6144;
    if (i < 2048) { int col = i >> 5, k = i & 31;
        a1P[i] = (__bf16)((k >= 6 && k < 10) ? W_a1[(k - 6) * AUXE_ + col] : 0.f); return; }
    i -= 2048;
    if (i < 8192) { int col = i >> 5, k = i & 31;
        e1P[i] = (__bf16)((k >= 10 && k < 13) ? W_e1[(k - 10) * D_ + col] : 0.f); return; }
    i -= 8192;
    if (i < 36864) {  // ts2: COLS=192, KS=6
        int tile = i >> 9, lr = (i >> 5) & 15, kk = i & 31;
        int ct = tile / 6, ks = tile % 6;
        ts2T[i] = (__bf16)W_ts2[(ks * 32 + kk) * TSE_ + ct * 16 + lr]; return; }
    i -= 36864;
    if (i < 4096) {   // a2: COLS=64, KS=2
        int tile = i >> 9, lr = (i >> 5) & 15, kk = i & 31;
        int ct = tile / 2, ks = tile % 2;
        a2T[i] = (__bf16)W_a2[(ks * 32 + kk) * AUXE_ + ct * 16 + lr]; return; }
    i -= 4096;
    if (i < 65536) {  // e2: COLS=256, KS=8
        int tile = i >> 9, lr = (i >> 5) & 15, kk = i & 31;
        int ct = tile >> 3, ks = tile & 7;
        e2T[i] = (__bf16)W_e2[(ks * 32 + kk) * D_ + ct * 16 + lr]; return; }
    i -= 65536;
    if (i < 65536) {  // Wk
        int tile = i >> 9, lr = (i >> 5) & 15, kk = i & 31;
        int ct = tile >> 3, ks = tile & 7;
        WkT[i] = (__bf16)Wk[(ks * 32 + kk) * D_ + ct * 16 + lr]; return; }
    i -= 65536;
    if (i < 65536) {  // Wv
        int tile = i >> 9, lr = (i >> 5) & 15, kk = i & 31;
        int ct = tile >> 3, ks = tile & 7;
        WvT[i] = (__bf16)Wv[(ks * 32 + kk) * D_ + ct * 16 + lr]; return; }
    i -= 65536;
    if (i < 65536) {  // Wq (QSCALE pre-folded)
        int tile = i >> 9, lr = (i >> 5) & 15, kk = i & 31;
        int ct = tile >> 3, ks = tile & 7;
        WqT[i] = (__bf16)(Wq[(ks * 32 + kk) * D_ + ct * 16 + lr] * QSCALE_); return; }
    i -= 65536;
    {                 // Wo
        int tile = i >> 9, lr = (i >> 5) & 15, kk = i & 31;
        int ct = tile >> 3, ks = tile & 7;
        WoT[i] = (__bf16)Wo[(ks * 32 + kk) * D_ + ct * 16 + lr]; }
}

// --- fused kv chain (blk<1024) + q LN/proj (blk 1024..1087); independent paths
__global__ __launch_bounds__(256, 4) void kvq_mfma_kernel(
    const float* __restrict__ md, const float* __restrict__ na, const float* __restrict__ ea,
    const __bf16* __restrict__ ts1P, const __bf16* __restrict__ a1P,
    const __bf16* __restrict__ e1P,
    const float* __restrict__ b_ts1, const float* __restrict__ b_a1,
    const float* __restrict__ b_e1,
    const __bf16* __restrict__ ts2T, const __bf16* __restrict__ a2T,
    const __bf16* __restrict__ e2T,
    const float* __restrict__ b_ts2, const float* __restrict__ b_a2,
    const float* __restrict__ b_e2,
    const __bf16* __restrict__ WkT, const float* __restrict__ bk,
    const __bf16* __restrict__ WvT, const float* __restrict__ bv,
    const float* __restrict__ pe, __bf16* __restrict__ Kb, __bf16* __restrict__ Vf,
    const float* __restrict__ x, const __bf16* __restrict__ WqT,
    const float* __restrict__ bq, const float* __restrict__ ln_g,
    const float* __restrict__ ln_b, __bf16* __restrict__ Qb) {
    int blk = blockIdx.x;
    int tid = threadIdx.x, lane = tid & 63;
    int wq = tid >> 6;
    int lr = lane & 15, lg = lane >> 4;

    // LDS union: kv {sA[1280] | sU[17536]} ; q {s_xn[8576]}
    __shared__ __bf16 sbuf[18816];

    int foff = lr * 32 + lg * 8;
    int crow0 = lg * 4;
    f32x4 z4 = {0.f, 0.f, 0.f, 0.f};

    if (blk >= 1024) {
        // ================= q path: x+pe, row-parallel LN, MFMA Q proj =======
        int qblk = blk - 1024;
        int t0 = (qblk & 15) * 32;
        int b = qblk >> 4;
        __bf16* s_xn = sbuf;

        {
            int row = tid >> 3, sub = tid & 7;
            size_t roff = ((size_t)b * T_ + t0 + row) * D_;
            const float* pr = pe + (t0 + row) * D_;
            f32x4 vv[8];
            float s1 = 0.f, s2 = 0.f;
#pragma unroll
            for (int q4 = 0; q4 < 8; ++q4) {
                int c = q4 * 32 + sub * 4;
                f32x4 xv = *(const f32x4*)(x + roff + c);
                f32x4 pv = *(const f32x4*)(pr + c);
                f32x4 t4;
#pragma unroll
                for (int j = 0; j < 4; ++j) {
                    t4[j] = xv[j] + pv[j];
                    s1 += t4[j];
                    s2 += t4[j] * t4[j];
                }
                vv[q4] = t4;
            }
#pragma unroll
            for (int o = 1; o <= 4; o <<= 1) {
                s1 += __shfl_xor(s1, o, 64);
                s2 += __shfl_xor(s2, o, 64);
            }
            float mu = s1 * (1.f / D_);
            float var = s2 * (1.f / D_) - mu * mu;
            float rs = rsqrtf(var + 1e-6f);
#pragma unroll
            for (int q4 = 0; q4 < 8; ++q4) {
                int c = q4 * 32 + sub * 4;
                f32x4 g4 = *(const f32x4*)(ln_g + c);
                f32x4 b4 = *(const f32x4*)(ln_b + c);
#pragma unroll
                for (int j = 0; j < 4; ++j)
                    s_xn[row * SK_S + c + j] = (__bf16)((vv[q4][j] - mu) * rs * g4[j] + b4[j]);
            }
        }
        __syncthreads();

        f32x4 qa[2][4];
#pragma unroll
        for (int i = 0; i < 4; ++i) { qa[0][i] = z4; qa[1][i] = z4; }
        const __bf16* qbse = WqT + (size_t)(wq * 4) * 8 * 512 + foff;
#pragma unroll
        for (int ks = 0; ks < 8; ++ks) {
            bf16x8 af0 = *(const bf16x8*)(s_xn + lr * SK_S + ks * 32 + lg * 8);
            bf16x8 af1 = *(const bf16x8*)(s_xn + (16 + lr) * SK_S + ks * 32 + lg * 8);
#pragma unroll
            for (int i = 0; i < 4; ++i) {
                bf16x8 b8 = *(const bf16x8*)(qbse + i * 4096 + ks * 512);
                qa[0][i] = __builtin_amdgcn_mfma_f32_16x16x32_bf16(af0, b8, qa[0][i], 0, 0, 0);
                qa[1][i] = __builtin_amdgcn_mfma_f32_16x16x32_bf16(af1, b8, qa[1][i], 0, 0, 0);
            }
        }
#pragma unroll
        for (int i = 0; i < 4; ++i) {
            int gcol = wq * 64 + i * 16 + lr;
            float bias = bq[gcol] * QSCALE_;
#pragma unroll
            for (int rf = 0; rf < 2; ++rf)
#pragma unroll
                for (int r = 0; r < 4; ++r)
                    Qb[((size_t)b * T_ + t0 + rf * 16 + crow0 + r) * D_ + gcol] =
                        (__bf16)(qa[rf][i][r] + bias);
        }
        return;
    }

    // ================= kv path =================
    int t0 = (blk & 15) * 32;
    int n = (blk >> 4) & 15;
    int b = blk >> 8;
    __bf16* sA = sbuf;                   // [32*40]
    __bf16* sU = sbuf + 1280;
    __bf16* hts = sU;                    // [32][204]
    __bf16* haux = sU + 6528;            // [32][76]
    __bf16* hedge = sU + 8960;           // [32][268]
    __bf16* skey = sU;                   // [32][268]
    __bf16* sval = sU + 8576;            // [32][268]

    for (int i = tid; i < 32 * 40; i += 256) sA[i] = (__bf16)0.f;
    __syncthreads();
    {
        int t = tid & 31, c0 = tid >> 5;
        size_t bn = (size_t)b * N_ + n;
        for (int c = c0; c < 13; c += 8) {
            float v;
            if (c < 6) v = md[(bn * CTS_ + c) * T_ + t0 + t];
            else if (c < 10) v = na[(bn * CN_ + (c - 6)) * T_ + t0 + t];
            else v = ea[(bn * CE_ + (c - 10)) * T_ + t0 + t];
            sA[t * 40 + c] = (__bf16)v;
        }
    }
    __syncthreads();

    bf16x8 a1f0 = *(const bf16x8*)(sA + lr * 40 + lg * 8);
    bf16x8 a1f1 = *(const bf16x8*)(sA + (16 + lr) * 40 + lg * 8);

    // ---- phase 2: first layers (K=32)
    {
        bool isTs = (wq < 3);
#pragma unroll
        for (int i = 0; i < 4; ++i) {
            int ctn = wq * 4 + i;
            const __bf16* src = isTs ? (ts1P + ctn * 512) : (a1P + (ctn - 12) * 512);
            bf16x8 bf = *(const bf16x8*)(src + foff);
            f32x4 c0 = __builtin_amdgcn_mfma_f32_16x16x32_bf16(a1f0, bf, z4, 0, 0, 0);
            f32x4 c1 = __builtin_amdgcn_mfma_f32_16x16x32_bf16(a1f1, bf, z4, 0, 0, 0);
            if (isTs) {
                int gcol = ctn * 16 + lr;
                float bias = b_ts1[gcol];
#pragma unroll
                for (int r = 0; r < 4; ++r) {
                    hts[(crow0 + r) * HTS_S + gcol] = (__bf16)fmaxf(c0[r] + bias, 0.f);
                    hts[(16 + crow0 + r) * HTS_S + gcol] = (__bf16)fmaxf(c1[r] + bias, 0.f);
                }
            } else {
                int acol = (ctn - 12) * 16 + lr;
                float bias = b_a1[acol];
#pragma unroll
                for (int r = 0; r < 4; ++r) {
                    haux[(crow0 + r) * HAUX_S + acol] = (__bf16)fmaxf(c0[r] + bias, 0.f);
                    haux[(16 + crow0 + r) * HAUX_S + acol] = (__bf16)fmaxf(c1[r] + bias, 0.f);
                }
            }
        }
#pragma unroll
        for (int i = 0; i < 4; ++i) {
            int cte = wq * 4 + i;
            bf16x8 bf = *(const bf16x8*)(e1P + cte * 512 + foff);
            f32x4 c0 = __builtin_amdgcn_mfma_f32_16x16x32_bf16(a1f0, bf, z4, 0, 0, 0);
            f32x4 c1 = __builtin_amdgcn_mfma_f32_16x16x32_bf16(a1f1, bf, z4, 0, 0, 0);
            int gcol = cte * 16 + lr;
            float bias = b_e1[gcol];
#pragma unroll
            for (int r = 0; r < 4; ++r) {
                hedge[(crow0 + r) * HED_S + gcol] = (__bf16)fmaxf(c0[r] + bias, 0.f);
                hedge[(16 + crow0 + r) * HED_S + gcol] = (__bf16)fmaxf(c1[r] + bias, 0.f);
            }
        }
    }
    __syncthreads();

    // ---- phase 3a: edge second layer
    f32x4 eacc[2][4];
#pragma unroll
    for (int i = 0; i < 4; ++i) { eacc[0][i] = z4; eacc[1][i] = z4; }
    {
        const __bf16* ebase = e2T + (size_t)(wq * 4) * 8 * 512 + foff;
        bf16x8 bcur[4];
#pragma unroll
        for (int i = 0; i < 4; ++i) bcur[i] = *(const bf16x8*)(ebase + i * 4096);
#pragma unroll 1
        for (int ks = 0; ks < 8; ++ks) {
            bf16x8 bnext[4];
            if (ks < 7) {
#pragma unroll
                for (int i = 0; i < 4; ++i)
                    bnext[i] = *(const bf16x8*)(ebase + i * 4096 + (ks + 1) * 512);
            }
            __builtin_amdgcn_sched_barrier(0);
            bf16x8 af0 = *(const bf16x8*)(hedge + lr * HED_S + ks * 32 + lg * 8);
            bf16x8 af1 = *(const bf16x8*)(hedge + (16 + lr) * HED_S + ks * 32 + lg * 8);
#pragma unroll
            for (int i = 0; i < 4; ++i) {
                eacc[0][i] = __builtin_amdgcn_mfma_f32_16x16x32_bf16(af0, bcur[i], eacc[0][i], 0, 0, 0);
                eacc[1][i] = __builtin_amdgcn_mfma_f32_16x16x32_bf16(af1, bcur[i], eacc[1][i], 0, 0, 0);
            }
            if (ks < 7) {
#pragma unroll
                for (int i = 0; i < 4; ++i) bcur[i] = bnext[i];
            }
        }
    }

    // ---- phase 3b: nbr second layer
    f32x4 nacc[2][4];
#pragma unroll
    for (int i = 0; i < 4; ++i) { nacc[0][i] = z4; nacc[1][i] = z4; }
    if (wq < 3) {
        const __bf16* nbase = ts2T + (size_t)(wq * 4) * 6 * 512 + foff;
        bf16x8 bcur[4];
#pragma unroll
        for (int i = 0; i < 4; ++i) bcur[i] = *(const bf16x8*)(nbase + i * 3072);
#pragma unroll 1
        for (int ks = 0; ks < 6; ++ks) {
            bf16x8 bnext[4];
            if (ks < 5) {
#pragma unroll
                for (int i = 0; i < 4; ++i)
                    bnext[i] = *(const bf16x8*)(nbase + i * 3072 + (ks + 1) * 512);
            }
            __builtin_amdgcn_sched_barrier(0);
            bf16x8 af0 = *(const bf16x8*)(hts + lr * HTS_S + ks * 32 + lg * 8);
            bf16x8 af1 = *(const bf16x8*)(hts + (16 + lr) * HTS_S + ks * 32 + lg * 8);
#pragma unroll
            for (int i = 0; i < 4; ++i) {
                nacc[0][i] = __builtin_amdgcn_mfma_f32_16x16x32_bf16(af0, bcur[i], nacc[0][i], 0, 0, 0);
                nacc[1][i] = __builtin_amdgcn_mfma_f32_16x16x32_bf16(af1, bcur[i], nacc[1][i], 0, 0, 0);
            }
            if (ks < 5) {
#pragma unroll
                for (int i = 0; i < 4; ++i) bcur[i] = bnext[i];
            }
        }
    } else {
#pragma unroll
        for (int ks = 0; ks < 2; ++ks) {
            bf16x8 af0 = *(const bf16x8*)(haux + lr * HAUX_S + ks * 32 + lg * 8);
            bf16x8 af1 = *(const bf16x8*)(haux + (16 + lr) * HAUX_S + ks * 32 + lg * 8);
#pragma unroll
            for (int i = 0; i < 4; ++i) {
                bf16x8 bf = *(const bf16x8*)(a2T + (i * 2 + ks) * 512 + foff);
                nacc[0][i] = __builtin_amdgcn_mfma_f32_16x16x32_bf16(af0, bf, nacc[0][i], 0, 0, 0);
                nacc[1][i] = __builtin_amdgcn_mfma_f32_16x16x32_bf16(af1, bf, nacc[1][i], 0, 0, 0);
            }
        }
    }
    __syncthreads();

    // ---- phase 3c: key/val assembly
#pragma unroll
    for (int i = 0; i < 4; ++i) {
        int gcol = wq * 64 + i * 16 + lr;
        float nb_bias = (wq < 3) ? b_ts2[gcol] : b_a2[gcol - 192];
        float ed_bias = b_e2[gcol];
#pragma unroll
        for (int rf = 0; rf < 2; ++rf)
#pragma unroll
            for (int r = 0; r < 4; ++r) {
                int row = rf * 16 + crow0 + r;
                float p = pe[(t0 + row) * D_ + gcol];
                float nb = nacc[rf][i][r] + nb_bias;
                float ed = eacc[rf][i][r] + ed_bias;
                skey[row * SK_S + gcol] = (__bf16)(nb * ed + p);
                sval[row * SK_S + gcol] = (__bf16)(nb + p);
            }
    }
    __syncthreads();

    size_t key0 = (size_t)n * T_ + t0;

    // ---- phase 4a: K projection
    {
        const __bf16* kbse = WkT + (size_t)(wq * 4) * 8 * 512 + foff;
        f32x4 ka[2][4];
#pragma unroll
        for (int i = 0; i < 4; ++i) { ka[0][i] = z4; ka[1][i] = z4; }
        bf16x8 bcur[4];
#pragma unroll
        for (int i = 0; i < 4; ++i) bcur[i] = *(const bf16x8*)(kbse + i * 4096);
#pragma unroll 1
        for (int ks = 0; ks < 8; ++ks) {
            bf16x8 bnext[4];
            if (ks < 7) {
#pragma unroll
                for (int i = 0; i < 4; ++i)
                    bnext[i] = *(const bf16x8*)(kbse + i * 4096 + (ks + 1) * 512);
            }
            __builtin_amdgcn_sched_barrier(0);
            bf16x8 af0 = *(const bf16x8*)(skey + lr * SK_S + ks * 32 + lg * 8);
            bf16x8 af1 = *(const bf16x8*)(skey + (16 + lr) * SK_S + ks * 32 + lg * 8);
#pragma unroll
            for (int i = 0; i < 4; ++i) {
                ka[0][i] = __builtin_amdgcn_mfma_f32_16x16x32_bf16(af0, bcur[i], ka[0][i], 0, 0, 0);
                ka[1][i] = __builtin_amdgcn_mfma_f32_16x16x32_bf16(af1, bcur[i], ka[1][i], 0, 0, 0);
            }
            if (ks < 7) {
#pragma unroll
                for (int i = 0; i < 4; ++i) bcur[i] = bnext[i];
            }
        }
#pragma unroll
        for (int i = 0; i < 4; ++i) {
            int gcol = wq * 64 + i * 16 + lr;
            float kbias = bk[gcol];
            int h = gcol >> 5, dd = gcol & 31;
            size_t bh = (size_t)b * H_ + h;
#pragma unroll
            for (int rf = 0; rf < 2; ++rf) {
                int crow = rf * 16 + crow0;
#pragma unroll
                for (int r = 0; r < 4; ++r)
                    Kb[(bh * NT_ + key0 + crow + r) * DK_ + dd] = (__bf16)(ka[rf][i][r] + kbias);
            }
        }
    }

    // ---- phase 4b: V projection
    {
        const __bf16* vbse = WvT + (size_t)(wq * 4) * 8 * 512 + foff;
        f32x4 va[2][4];
#pragma unroll
        for (int i = 0; i < 4; ++i) { va[0][i] = z4; va[1][i] = z4; }
        bf16x8 bcur[4];
#pragma unroll
        for (int i = 0; i < 4; ++i) bcur[i] = *(const bf16x8*)(vbse + i * 4096);
#pragma unroll 1
        for (int ks = 0; ks < 8; ++ks) {
            bf16x8 bnext[4];
            if (ks < 7) {
#pragma unroll
                for (int i = 0; i < 4; ++i)
                    bnext[i] = *(const bf16x8*)(vbse + i * 4096 + (ks + 1) * 512);
            }
            __builtin_amdgcn_sched_barrier(0);
            bf16x8 af0 = *(const bf16x8*)(sval + lr * SK_S + ks * 32 + lg * 8);
            bf16x8 af1 = *(const bf16x8*)(sval + (16 + lr) * SK_S + ks * 32 + lg * 8);
#pragma unroll
            for (int i = 0; i < 4; ++i) {
                va[0][i] = __builtin_amdgcn_mfma_f32_16x16x32_bf16(af0, bcur[i], va[0][i], 0, 0, 0);
                va[1][i] = __builtin_amdgcn_mfma_f32_16x16x32_bf16(af1, bcur[i], va[1][i], 0, 0, 0);
            }
            if (ks < 7) {
#pragma unroll
                for (int i = 0; i < 4; ++i) bcur[i] = bnext[i];
            }
        }
#pragma unroll
        for (int i = 0; i < 4; ++i) {
            int gcol = wq * 64 + i * 16 + lr;
            float vbias = bv[gcol];
            int h = gcol >> 5, dd = gcol & 31;
            size_t bh = (size_t)b * H_ + h;
#pragma unroll
            for (int rf = 0; rf < 2; ++rf) {
                int crow = rf * 16 + crow0;
                __bf16 tmp[4];
#pragma unroll
                for (int r = 0; r < 4; ++r) tmp[r] = (__bf16)(va[rf][i][r] + vbias);
                size_t kg = key0 + crow;
                int within = (int)(kg & 63);
                int vks = within >> 4, vl5 = (within >> 3) & 1, j0 = within & 7;
                size_t tile = kg >> 6;
                size_t vaddr = ((bh * (NT_ / 64) + tile) * 4 + vks) * 512 +
                               (size_t)(vl5 * 32 + dd) * 8 + j0;
                *(ushort4*)(Vf + vaddr) = *(ushort4*)tmp;
            }
        }
    }
}

// ------- 32x32 MFMA attention: raw v_exp (exp2 domain), sbfe mask, ones-MFMA l
// Opart stored bf16 (unnormalized partial O; bf16 rel-err ~0.4% << threshold)
__global__ __launch_bounds__(256, 4) void attn_mfma_kernel(
    const __bf16* __restrict__ Qb, const __bf16* __restrict__ Kb,
    const __bf16* __restrict__ Vf, const ull* __restrict__ bitsT,
    __bf16* __restrict__ Opart, float* __restrict__ Lpart) {
    int blk = blockIdx.x;
    int kh = blk & (SPLIT_ - 1);
    int qt = (blk >> 3) & 3;
    int h = (blk >> 5) & 7;
    int b = blk >> 8;
    int tid = threadIdx.x, lane = tid & 63, w = tid >> 6;
    int lq = lane & 31, l5 = lane >> 5;

    const size_t bh = (size_t)b * H_ + h;
    const int TILES = KWORDS_ / SPLIT_;   // 16

    int qglob = qt * 128 + w * 32 + lq;
    const __bf16* qbase = Qb + ((size_t)b * T_ + qglob) * D_ + h * DK_ + l5 * 8;
    bf16x8 qf0 = *(const bf16x8*)(qbase);
    bf16x8 qf1 = *(const bf16x8*)(qbase + 16);

    const __bf16* kp = Kb + bh * NT_ * DK_ + (size_t)(kh * TILES) * 64 * DK_;
    const __bf16* vp = Vf + (bh * (NT_ / 64) + (size_t)(kh * TILES)) * 2048;
    const ull* mp = bitsT + (size_t)b * KWORDS_ * T_ + (size_t)(kh * TILES) * T_ + qglob;

    int k00 = lq * DK_ + l5 * 8;
    int k01 = k00 + 16;
    int k10 = (32 + lq) * DK_ + l5 * 8;
    int k11 = k10 + 16;
    int shamt = 4 * l5;

    f32x16 acc, acc_l, zv;
#pragma unroll
    for (int i = 0; i < 16; ++i) { acc[i] = 0.f; acc_l[i] = 0.f; zv[i] = 0.f; }
    union { uint u[4]; bf16x8 v; } onesf;
    onesf.u[0] = 0x3F803F80u; onesf.u[1] = 0x3F803F80u;
    onesf.u[2] = 0x3F803F80u; onesf.u[3] = 0x3F803F80u;

    bf16x8 kc0 = *(const bf16x8*)(kp + k00);
    bf16x8 kc1 = *(const bf16x8*)(kp + k01);
    bf16x8 kc2 = *(const bf16x8*)(kp + k10);
    bf16x8 kc3 = *(const bf16x8*)(kp + k11);
    ull mw = *mp;

#pragma unroll 1
    for (int kt = 0; kt < TILES; ++kt) {
        bf16x8 vc0 = *(const bf16x8*)(vp + 0 * 512 + lane * 8);
        bf16x8 vc1 = *(const bf16x8*)(vp + 1 * 512 + lane * 8);
        bf16x8 vc2 = *(const bf16x8*)(vp + 2 * 512 + lane * 8);
        bf16x8 vc3 = *(const bf16x8*)(vp + 3 * 512 + lane * 8);
        bf16x8 kn0, kn1, kn2, kn3;
        ull mn = 0;
        if (kt + 1 < TILES) {
            kn0 = *(const bf16x8*)(kp + 2048 + k00);
            kn1 = *(const bf16x8*)(kp + 2048 + k01);
            kn2 = *(const bf16x8*)(kp + 2048 + k10);
            kn3 = *(const bf16x8*)(kp + 2048 + k11);
            mn = mp[T_];
        }
        __builtin_amdgcn_sched_barrier(0);

        ull sh = mw >> shamt;

#pragma unroll
        for (int s = 0; s < 2; ++s) {
            f32x16 sc = __builtin_amdgcn_mfma_f32_32x32x16_bf16(
                s ? kc2 : kc0, qf0, zv, 0, 0, 0);
            sc = __builtin_amdgcn_mfma_f32_32x32x16_bf16(
                s ? kc3 : kc1, qf1, sc, 0, 0, 0);

            uint ms = (uint)(sh >> (32 * s));
            float p[16];
#pragma unroll
            for (int r = 0; r < 16; ++r) {
                int pos = (r & 3) + 8 * (r >> 2);
                float e = __builtin_amdgcn_exp2f(sc[r]);                 // raw v_exp
                int mb = __builtin_amdgcn_sbfe((int)ms, (uint)pos, 1u);  // 0 or -1
                p[r] = __uint_as_float(__float_as_uint(e) & (uint)mb);
            }

#pragma unroll
            for (int h2 = 0; h2 < 2; ++h2) {
                uint w0, w1, w2, w3;
                asm("v_cvt_pk_bf16_f32 %0, %1, %2" : "=v"(w0) : "v"(p[8 * h2 + 0]), "v"(p[8 * h2 + 1]));
                asm("v_cvt_pk_bf16_f32 %0, %1, %2" : "=v"(w1) : "v"(p[8 * h2 + 2]), "v"(p[8 * h2 + 3]));
                asm("v_cvt_pk_bf16_f32 %0, %1, %2" : "=v"(w2) : "v"(p[8 * h2 + 4]), "v"(p[8 * h2 + 5]));
                asm("v_cvt_pk_bf16_f32 %0, %1, %2" : "=v"(w3) : "v"(p[8 * h2 + 6]), "v"(p[8 * h2 + 7]));
                asm volatile("v_permlane32_swap_b32 %0, %1" : "+v"(w0), "+v"(w2));
                asm volatile("v_permlane32_swap_b32 %0, %1" : "+v"(w1), "+v"(w3));
                union { uint u[4]; bf16x8 v; } pa;
                pa.u[0] = w0; pa.u[1] = w1; pa.u[2] = w2; pa.u[3] = w3;
                bf16x8 vfr = (s == 0) ? (h2 == 0 ? vc0 : vc1) : (h2 == 0 ? vc2 : vc3);
                acc = __builtin_amdgcn_mfma_f32_32x32x16_bf16(pa.v, vfr, acc, 0, 0, 0);
                acc_l = __builtin_amdgcn_mfma_f32_32x32x16_bf16(pa.v, onesf.v, acc_l, 0, 0, 0);
            }
        }

        kp += 2048;
        vp += 2048;
        mp += T_;
        if (kt + 1 < TILES) {
            kc0 = kn0; kc1 = kn1; kc2 = kn2; kc3 = kn3;
            mw = mn;
        }
    }

    size_t obase = (((size_t)kh * B_ + b) * H_ + h) * T_ + qt * 128 + w * 32;
#pragma unroll
    for (int r = 0; r < 16; ++r) {
        int q = (r & 3) + 8 * (r >> 2) + 4 * l5;
        Opart[(obase + q) * DK_ + lq] = (__bf16)acc[r];
    }
    if (lq == 0) {
#pragma unroll
        for (int r = 0; r < 16; ++r) {
            int q = (r & 3) + 8 * (r >> 2) + 4 * l5;
            Lpart[obase + q] = acc_l[r];
        }
    }
}

// ------ out = (x+pe) + (merge of bf16 Opart / f32 Lpart)@Wo + bo, grid 64
__global__ __launch_bounds__(256) void out_mfma_kernel(
    const __bf16* __restrict__ Opart, const float* __restrict__ Lpart,
    const float* __restrict__ x, const float* __restrict__ pe,
    const __bf16* __restrict__ WoT, const float* __restrict__ bo,
    float* __restrict__ out) {
    int blk = blockIdx.x;
    int t0 = (blk & 15) * 32;
    int b = blk >> 4;
    int tid = threadIdx.x, lane = tid & 63;
    int wq = tid >> 6, lr = lane & 15, lg = lane >> 4;

    __shared__ __bf16 sc_[32 * SK_S];
    __shared__ float sLinv[32 * 8];
    size_t ps = (size_t)B_ * H_ * T_;

    // phase A: 1/L per (row, head)
    {
        int row = tid >> 3, hh = tid & 7;
        size_t base = ((size_t)b * H_ + hh) * T_ + t0 + row;
        float L = 0.f;
#pragma unroll
        for (int s = 0; s < SPLIT_; ++s) L += Lpart[s * ps + base];
        sLinv[row * 8 + hh] = 1.0f / L;
    }
    __syncthreads();

    // phase B: merge bf16 Opart -> ctx bf16 in LDS
    for (int idx = tid; idx < 32 * 64; idx += 256) {
        int r = idx >> 6, g = idx & 63;
        int hh = g >> 3, d4 = (g & 7) * 4;
        size_t base = (((size_t)b * H_ + hh) * T_ + t0 + r) * DK_ + d4;
        float o0 = 0.f, o1 = 0.f, o2 = 0.f, o3 = 0.f;
#pragma unroll
        for (int s = 0; s < SPLIT_; ++s) {
            union { ushort4 u; __bf16 h[4]; } cv;
            cv.u = *(const ushort4*)(Opart + s * ps * DK_ + base);
            o0 += (float)cv.h[0]; o1 += (float)cv.h[1];
            o2 += (float)cv.h[2]; o3 += (float)cv.h[3];
        }
        float li = sLinv[r * 8 + hh];
        int c = hh * 32 + d4;
        sc_[r * SK_S + c + 0] = (__bf16)(o0 * li);
        sc_[r * SK_S + c + 1] = (__bf16)(o1 * li);
        sc_[r * SK_S + c + 2] = (__bf16)(o2 * li);
        sc_[r * SK_S + c + 3] = (__bf16)(o3 * li);
    }
    __syncthreads();

    int foff = lr * 32 + lg * 8;
    int crow0 = lg * 4;
    f32x4 z4 = {0.f, 0.f, 0.f, 0.f};
    f32x4 oa[2][4];
#pragma unroll
    for (int i = 0; i < 4; ++i) { oa[0][i] = z4; oa[1][i] = z4; }
    const __bf16* obse = WoT + (size_t)(wq * 4) * 8 * 512 + foff;
#pragma unroll
    for (int ks = 0; ks < 8; ++ks) {
        bf16x8 af0 = *(const bf16x8*)(sc_ + lr * SK_S + ks * 32 + lg * 8);
        bf16x8 af1 = *(const bf16x8*)(sc_ + (16 + lr) * SK_S + ks * 32 + lg * 8);
#pragma unroll
        for (int i = 0; i < 4; ++i) {
            bf16x8 b8 = *(const bf16x8*)(obse + i * 4096 + ks * 512);
            oa[0][i] = __builtin_amdgcn_mfma_f32_16x16x32_bf16(af0, b8, oa[0][i], 0, 0, 0);
            oa[1][i] = __builtin_amdgcn_mfma_f32_16x16x32_bf16(af1, b8, oa[1][i], 0, 0, 0);
        }
    }
#pragma unroll
    for (int i = 0; i < 4; ++i) {
        int gcol = wq * 64 + i * 16 + lr;
        float bias = bo[gcol];
#pragma unroll
        for (int rf = 0; rf < 2; ++rf)
#pragma unroll
            for (int r = 0; r < 4; ++r) {
                int t = t0 + rf * 16 + crow0 + r;
                size_t off = ((size_t)b * T_ + t) * D_ + gcol;
                out[off] = x[off] + pe[t * D_ + gcol] + oa[rf][i][r] + bias;
            }
    }
}

// ---------------------------------------------------------------- launcher
extern "C" void kernel_launch(void* const* d_in, const int* in_sizes, int n_in,
                              void* d_out, int out_size, void* d_ws, size_t ws_size,
                              hipStream_t stream) {
    const float* x = (const float*)d_in[0];
    const float* md = (const float*)d_in[1];
    const float* na = (const float*)d_in[2];
    const float* ea = (const float*)d_in[3];
    const int* mask = (const int*)d_in[4];
    const float* W_ts1 = (const float*)d_in[5];
    const float* b_ts1 = (const float*)d_in[6];
    const float* W_ts2 = (const float*)d_in[7];
    const float* b_ts2 = (const float*)d_in[8];
    const float* W_a1 = (const float*)d_in[9];
    const float* b_a1 = (const float*)d_in[10];
    const float* W_a2 = (const float*)d_in[11];
    const float* b_a2 = (const float*)d_in[12];
    const float* W_e1 = (const float*)d_in[13];
    const float* b_e1 = (const float*)d_in[14];
    const float* W_e2 = (const float*)d_in[15];
    const float* b_e2 = (const float*)d_in[16];
    const float* Wq = (const float*)d_in[17];
    const float* bq = (const float*)d_in[18];
    const float* Wk = (const float*)d_in[19];
    const float* bk = (const float*)d_in[20];
    const float* Wv = (const float*)d_in[21];
    const float* bv = (const float*)d_in[22];
    const float* Wo = (const float*)d_in[23];
    const float* bo = (const float*)d_in[24];
    const float* ln_g = (const float*)d_in[25];
    const float* ln_b = (const float*)d_in[26];
    float* out = (float*)d_out;

    char* ws = (char*)d_ws;
    float* pe = (float*)ws;      ws += (size_t)T_ * D_ * 4;
    ull* bitsT = (ull*)ws;       ws += (size_t)B_ * KWORDS_ * T_ * 8;    // 2 MB
    __bf16* Kb = (__bf16*)ws;    ws += (size_t)B_ * H_ * NT_ * DK_ * 2;  // 16 MB
    __bf16* Vf = (__bf16*)ws;    ws += (size_t)B_ * H_ * NT_ * DK_ * 2;  // 16 MB
    __bf16* Qb = (__bf16*)ws;    ws += (size_t)B_ * T_ * D_ * 2;         // 1 MB
    __bf16* Opart = (__bf16*)ws; ws += (size_t)SPLIT_ * B_ * H_ * T_ * DK_ * 2;  // 8 MB
    float* Lpart = (float*)ws;   ws += (size_t)SPLIT_ * B_ * H_ * T_ * 4;
    // bf16 prepped weights
    __bf16* ts1P = (__bf16*)ws; ws += 6144 * 2;
    __bf16* a1P = (__bf16*)ws;  ws += 2048 * 2;
    __bf16* e1P = (__bf16*)ws;  ws += 8192 * 2;
    __bf16* ts2T = (__bf16*)ws; ws += 36864 * 2;
    __bf16* a2T = (__bf16*)ws;  ws += 4096 * 2;
    __bf16* e2T = (__bf16*)ws;  ws += 65536 * 2;
    __bf16* WkT = (__bf16*)ws;  ws += 65536 * 2;
    __bf16* WvT = (__bf16*)ws;  ws += 65536 * 2;
    __bf16* WqT = (__bf16*)ws;  ws += 65536 * 2;
    __bf16* WoT = (__bf16*)ws;  ws += 65536 * 2;

    prep_kernel<<<4064, 256, 0, stream>>>(mask, bitsT, pe,
                                          W_ts1, W_a1, W_e1, W_ts2, W_a2, W_e2,
                                          Wk, Wv, Wq, Wo,
                                          ts1P, a1P, e1P, ts2T, a2T, e2T,
                                          WkT, WvT, WqT, WoT);
    kvq_mfma_kernel<<<B_ * N_ * (T_ / 32) + B_ * (T_ / 32), 256, 0, stream>>>(
        md, na, ea, ts1P, a1P, e1P, b_ts1, b_a1, b_e1,
        ts2T, a2T, e2T, b_ts2, b_a2, b_e2, WkT, bk, WvT, bv, pe, Kb, Vf,
        x, WqT, bq, ln_g, ln_b, Qb);
    attn_mfma_kernel<<<B_ * H_ * (T_ / 128) * SPLIT_, 256, 0, stream>>>(
        Qb, Kb, Vf, bitsT, Opart, Lpart);
    out_mfma_kernel<<<B_ * (T_ / 32), 256, 0, stream>>>(Opart, Lpart, x, pe, WoT, bo, out);
}

// Round 26
// 108.426 us; speedup vs baseline: 1.2241x; 1.0057x over previous
//
#include <hip/hip_runtime.h>
#include <hip/hip_bf16.h>

#define B_ 4
#define T_ 512
#define N_ 16
#define D_ 256
#define H_ 8
#define DK_ 32
#define NT_ (N_ * T_)
#define CTS_ 6
#define CN_ 4
#define CE_ 3
#define TSE_ 192
#define AUXE_ 64
#define SPLIT_ 8
#define KWORDS_ (NT_ / 64)   // 128 mask words per row

// Q pre-scale: (1/sqrt(32)) * log2(e) -> scores in exp2 domain, raw v_exp_f32
#define QSCALE_ 0.2550689747f

// padded LDS strides (elements): stride/2 dwords ≡ 6 mod 32 -> conflict-free b128
#define HTS_S 204
#define HAUX_S 76
#define HED_S 268
#define SK_S 268

typedef unsigned long long ull;
typedef unsigned int uint;
typedef __bf16 bf16x8 __attribute__((ext_vector_type(8)));
typedef float f32x4 __attribute__((ext_vector_type(4)));
typedef float f32x16 __attribute__((ext_vector_type(16)));

// ---- fused prep: pe table (blk<512) | maskbits (512..2559) | wprep (2560..4063)
__global__ __launch_bounds__(256) void prep_kernel(
    const int* __restrict__ mask, ull* __restrict__ bitsT, float* __restrict__ pe,
    const float* __restrict__ W_ts1, const float* __restrict__ W_a1,
    const float* __restrict__ W_e1, const float* __restrict__ W_ts2,
    const float* __restrict__ W_a2, const float* __restrict__ W_e2,
    const float* __restrict__ Wk, const float* __restrict__ Wv,
    const float* __restrict__ Wq, const float* __restrict__ Wo,
    __bf16* __restrict__ ts1P, __bf16* __restrict__ a1P, __bf16* __restrict__ e1P,
    __bf16* __restrict__ ts2T, __bf16* __restrict__ a2T, __bf16* __restrict__ e2T,
    __bf16* __restrict__ WkT, __bf16* __restrict__ WvT,
    __bf16* __restrict__ WqT, __bf16* __restrict__ WoT) {
    int blk = blockIdx.x;
    int tid = threadIdx.x;
    if (blk < 512) {
        int t = blk, d = tid;
        int j = d >> 1;
        float div = expf((float)(2 * j) * (-9.210340371976184f / 256.0f));
        float a = (float)t * div;
        pe[t * D_ + d] = (d & 1) ? cosf(a) : sinf(a);
        return;
    }
    if (blk < 2560) {
        int row = blk - 512;
        int b = row >> 9, t = row & (T_ - 1);
        const int* mrow = mask + (size_t)row * NT_;
        int lane = tid & 63, wave = tid >> 6;
        for (int it = 0; it < NT_ / 256; ++it) {
            int k = it * 256 + wave * 64 + lane;
            ull bal = __ballot(mrow[k] != 0);
            if (lane == 0) bitsT[((size_t)b * KWORDS_ + (k >> 6)) * T_ + t] = bal;
        }
        return;
    }
    int i = (blk - 2560) * 256 + tid;
    if (i < 6144) { int col = i >> 5, k = i & 31;
        ts1P[i] = (__bf16)(k < 6 ? W_ts1[k * TSE_ + col] : 0.f); return; }
    i -= 6144;
    if (i < 2048) { int col = i >> 5, k = i & 31;
        a1P[i] = (__bf16)((k >= 6 && k < 10) ? W_a1[(k - 6) * AUXE_ + col] : 0.f); return; }
    i -= 2048;
    if (i < 8192) { int col = i >> 5, k = i & 31;
        e1P[i] = (__bf16)((k >= 10 && k < 13) ? W_e1[(k - 10) * D_ + col] : 0.f); return; }
    i -= 8192;
    if (i < 36864) {  // ts2: COLS=192, KS=6
        int tile = i >> 9, lr = (i >> 5) & 15, kk = i & 31;
        int ct = tile / 6, ks = tile % 6;
        ts2T[i] = (__bf16)W_ts2[(ks * 32 + kk) * TSE_ + ct * 16 + lr]; return; }
    i -= 36864;
    if (i < 4096) {   // a2: COLS=64, KS=2
        int tile = i >> 9, lr = (i >> 5) & 15, kk = i & 31;
        int ct = tile / 2, ks = tile % 2;
        a2T[i] = (__bf16)W_a2[(ks * 32 + kk) * AUXE_ + ct * 16 + lr]; return; }
    i -= 4096;
    if (i < 65536) {  // e2: COLS=256, KS=8
        int tile = i >> 9, lr = (i >> 5) & 15, kk = i & 31;
        int ct = tile >> 3, ks = tile & 7;
        e2T[i] = (__bf16)W_e2[(ks * 32 + kk) * D_ + ct * 16 + lr]; return; }
    i -= 65536;
    if (i < 65536) {  // Wk
        int tile = i >> 9, lr = (i >> 5) & 15, kk = i & 31;
        int ct = tile >> 3, ks = tile & 7;
        WkT[i] = (__bf16)Wk[(ks * 32 + kk) * D_ + ct * 16 + lr]; return; }
    i -= 65536;
    if (i < 65536) {  // Wv
        int tile = i >> 9, lr = (i >> 5) & 15, kk = i & 31;
        int ct = tile >> 3, ks = tile & 7;
        WvT[i] = (__bf16)Wv[(ks * 32 + kk) * D_ + ct * 16 + lr]; return; }
    i -= 65536;
    if (i < 65536) {  // Wq (QSCALE pre-folded)
        int tile = i >> 9, lr = (i >> 5) & 15, kk = i & 31;
        int ct = tile >> 3, ks = tile & 7;
        WqT[i] = (__bf16)(Wq[(ks * 32 + kk) * D_ + ct * 16 + lr] * QSCALE_); return; }
    i -= 65536;
    {                 // Wo
        int tile = i >> 9, lr = (i >> 5) & 15, kk = i & 31;
        int ct = tile >> 3, ks = tile & 7;
        WoT[i] = (__bf16)Wo[(ks * 32 + kk) * D_ + ct * 16 + lr]; }
}

// --- fused kv chain (blk<1024) + q LN/proj (blk 1024..1087); independent paths
__global__ __launch_bounds__(256, 4) void kvq_mfma_kernel(
    const float* __restrict__ md, const float* __restrict__ na, const float* __restrict__ ea,
    const __bf16* __restrict__ ts1P, const __bf16* __restrict__ a1P,
    const __bf16* __restrict__ e1P,
    const float* __restrict__ b_ts1, const float* __restrict__ b_a1,
    const float* __restrict__ b_e1,
    const __bf16* __restrict__ ts2T, const __bf16* __restrict__ a2T,
    const __bf16* __restrict__ e2T,
    const float* __restrict__ b_ts2, const float* __restrict__ b_a2,
    const float* __restrict__ b_e2,
    const __bf16* __restrict__ WkT, const float* __restrict__ bk,
    const __bf16* __restrict__ WvT, const float* __restrict__ bv,
    const float* __restrict__ pe, __bf16* __restrict__ Kb, __bf16* __restrict__ Vf,
    const float* __restrict__ x, const __bf16* __restrict__ WqT,
    const float* __restrict__ bq, const float* __restrict__ ln_g,
    const float* __restrict__ ln_b, __bf16* __restrict__ Qb) {
    int blk = blockIdx.x;
    int tid = threadIdx.x, lane = tid & 63;
    int wq = tid >> 6;
    int lr = lane & 15, lg = lane >> 4;

    // LDS union: kv {sA[1280] | sU[17536]} ; q {s_xn[8576]}
    __shared__ __bf16 sbuf[18816];

    int foff = lr * 32 + lg * 8;
    int crow0 = lg * 4;
    f32x4 z4 = {0.f, 0.f, 0.f, 0.f};

    if (blk >= 1024) {
        // ================= q path: x+pe, row-parallel LN, MFMA Q proj =======
        int qblk = blk - 1024;
        int t0 = (qblk & 15) * 32;
        int b = qblk >> 4;
        __bf16* s_xn = sbuf;

        {
            int row = tid >> 3, sub = tid & 7;
            size_t roff = ((size_t)b * T_ + t0 + row) * D_;
            const float* pr = pe + (t0 + row) * D_;
            f32x4 vv[8];
            float s1 = 0.f, s2 = 0.f;
#pragma unroll
            for (int q4 = 0; q4 < 8; ++q4) {
                int c = q4 * 32 + sub * 4;
                f32x4 xv = *(const f32x4*)(x + roff + c);
                f32x4 pv = *(const f32x4*)(pr + c);
                f32x4 t4;
#pragma unroll
                for (int j = 0; j < 4; ++j) {
                    t4[j] = xv[j] + pv[j];
                    s1 += t4[j];
                    s2 += t4[j] * t4[j];
                }
                vv[q4] = t4;
            }
#pragma unroll
            for (int o = 1; o <= 4; o <<= 1) {
                s1 += __shfl_xor(s1, o, 64);
                s2 += __shfl_xor(s2, o, 64);
            }
            float mu = s1 * (1.f / D_);
            float var = s2 * (1.f / D_) - mu * mu;
            float rs = rsqrtf(var + 1e-6f);
#pragma unroll
            for (int q4 = 0; q4 < 8; ++q4) {
                int c = q4 * 32 + sub * 4;
                f32x4 g4 = *(const f32x4*)(ln_g + c);
                f32x4 b4 = *(const f32x4*)(ln_b + c);
#pragma unroll
                for (int j = 0; j < 4; ++j)
                    s_xn[row * SK_S + c + j] = (__bf16)((vv[q4][j] - mu) * rs * g4[j] + b4[j]);
            }
        }
        __syncthreads();

        f32x4 qa[2][4];
#pragma unroll
        for (int i = 0; i < 4; ++i) { qa[0][i] = z4; qa[1][i] = z4; }
        const __bf16* qbse = WqT + (size_t)(wq * 4) * 8 * 512 + foff;
#pragma unroll
        for (int ks = 0; ks < 8; ++ks) {
            bf16x8 af0 = *(const bf16x8*)(s_xn + lr * SK_S + ks * 32 + lg * 8);
            bf16x8 af1 = *(const bf16x8*)(s_xn + (16 + lr) * SK_S + ks * 32 + lg * 8);
#pragma unroll
            for (int i = 0; i < 4; ++i) {
                bf16x8 b8 = *(const bf16x8*)(qbse + i * 4096 + ks * 512);
                qa[0][i] = __builtin_amdgcn_mfma_f32_16x16x32_bf16(af0, b8, qa[0][i], 0, 0, 0);
                qa[1][i] = __builtin_amdgcn_mfma_f32_16x16x32_bf16(af1, b8, qa[1][i], 0, 0, 0);
            }
        }
#pragma unroll
        for (int i = 0; i < 4; ++i) {
            int gcol = wq * 64 + i * 16 + lr;
            float bias = bq[gcol] * QSCALE_;
#pragma unroll
            for (int rf = 0; rf < 2; ++rf)
#pragma unroll
                for (int r = 0; r < 4; ++r)
                    Qb[((size_t)b * T_ + t0 + rf * 16 + crow0 + r) * D_ + gcol] =
                        (__bf16)(qa[rf][i][r] + bias);
        }
        return;
    }

    // ================= kv path =================
    int t0 = (blk & 15) * 32;
    int n = (blk >> 4) & 15;
    int b = blk >> 8;
    __bf16* sA = sbuf;                   // [32*40]
    __bf16* sU = sbuf + 1280;
    __bf16* hts = sU;                    // [32][204]
    __bf16* haux = sU + 6528;            // [32][76]
    __bf16* hedge = sU + 8960;           // [32][268]
    __bf16* skey = sU;                   // [32][268]
    __bf16* sval = sU + 8576;            // [32][268]

    for (int i = tid; i < 32 * 40; i += 256) sA[i] = (__bf16)0.f;
    __syncthreads();
    {
        int t = tid & 31, c0 = tid >> 5;
        size_t bn = (size_t)b * N_ + n;
        for (int c = c0; c < 13; c += 8) {
            float v;
            if (c < 6) v = md[(bn * CTS_ + c) * T_ + t0 + t];
            else if (c < 10) v = na[(bn * CN_ + (c - 6)) * T_ + t0 + t];
            else v = ea[(bn * CE_ + (c - 10)) * T_ + t0 + t];
            sA[t * 40 + c] = (__bf16)v;
        }
    }
    __syncthreads();

    bf16x8 a1f0 = *(const bf16x8*)(sA + lr * 40 + lg * 8);
    bf16x8 a1f1 = *(const bf16x8*)(sA + (16 + lr) * 40 + lg * 8);

    // ---- phase 2: first layers (K=32)
    {
        bool isTs = (wq < 3);
#pragma unroll
        for (int i = 0; i < 4; ++i) {
            int ctn = wq * 4 + i;
            const __bf16* src = isTs ? (ts1P + ctn * 512) : (a1P + (ctn - 12) * 512);
            bf16x8 bf = *(const bf16x8*)(src + foff);
            f32x4 c0 = __builtin_amdgcn_mfma_f32_16x16x32_bf16(a1f0, bf, z4, 0, 0, 0);
            f32x4 c1 = __builtin_amdgcn_mfma_f32_16x16x32_bf16(a1f1, bf, z4, 0, 0, 0);
            if (isTs) {
                int gcol = ctn * 16 + lr;
                float bias = b_ts1[gcol];
#pragma unroll
                for (int r = 0; r < 4; ++r) {
                    hts[(crow0 + r) * HTS_S + gcol] = (__bf16)fmaxf(c0[r] + bias, 0.f);
                    hts[(16 + crow0 + r) * HTS_S + gcol] = (__bf16)fmaxf(c1[r] + bias, 0.f);
                }
            } else {
                int acol = (ctn - 12) * 16 + lr;
                float bias = b_a1[acol];
#pragma unroll
                for (int r = 0; r < 4; ++r) {
                    haux[(crow0 + r) * HAUX_S + acol] = (__bf16)fmaxf(c0[r] + bias, 0.f);
                    haux[(16 + crow0 + r) * HAUX_S + acol] = (__bf16)fmaxf(c1[r] + bias, 0.f);
                }
            }
        }
#pragma unroll
        for (int i = 0; i < 4; ++i) {
            int cte = wq * 4 + i;
            bf16x8 bf = *(const bf16x8*)(e1P + cte * 512 + foff);
            f32x4 c0 = __builtin_amdgcn_mfma_f32_16x16x32_bf16(a1f0, bf, z4, 0, 0, 0);
            f32x4 c1 = __builtin_amdgcn_mfma_f32_16x16x32_bf16(a1f1, bf, z4, 0, 0, 0);
            int gcol = cte * 16 + lr;
            float bias = b_e1[gcol];
#pragma unroll
            for (int r = 0; r < 4; ++r) {
                hedge[(crow0 + r) * HED_S + gcol] = (__bf16)fmaxf(c0[r] + bias, 0.f);
                hedge[(16 + crow0 + r) * HED_S + gcol] = (__bf16)fmaxf(c1[r] + bias, 0.f);
            }
        }
    }
    __syncthreads();

    // ---- phase 3a: edge second layer
    f32x4 eacc[2][4];
#pragma unroll
    for (int i = 0; i < 4; ++i) { eacc[0][i] = z4; eacc[1][i] = z4; }
    {
        const __bf16* ebase = e2T + (size_t)(wq * 4) * 8 * 512 + foff;
        bf16x8 bcur[4];
#pragma unroll
        for (int i = 0; i < 4; ++i) bcur[i] = *(const bf16x8*)(ebase + i * 4096);
#pragma unroll 1
        for (int ks = 0; ks < 8; ++ks) {
            bf16x8 bnext[4];
            if (ks < 7) {
#pragma unroll
                for (int i = 0; i < 4; ++i)
                    bnext[i] = *(const bf16x8*)(ebase + i * 4096 + (ks + 1) * 512);
            }
            __builtin_amdgcn_sched_barrier(0);
            bf16x8 af0 = *(const bf16x8*)(hedge + lr * HED_S + ks * 32 + lg * 8);
            bf16x8 af1 = *(const bf16x8*)(hedge + (16 + lr) * HED_S + ks * 32 + lg * 8);
#pragma unroll
            for (int i = 0; i < 4; ++i) {
                eacc[0][i] = __builtin_amdgcn_mfma_f32_16x16x32_bf16(af0, bcur[i], eacc[0][i], 0, 0, 0);
                eacc[1][i] = __builtin_amdgcn_mfma_f32_16x16x32_bf16(af1, bcur[i], eacc[1][i], 0, 0, 0);
            }
            if (ks < 7) {
#pragma unroll
                for (int i = 0; i < 4; ++i) bcur[i] = bnext[i];
            }
        }
    }

    // ---- phase 3b: nbr second layer
    f32x4 nacc[2][4];
#pragma unroll
    for (int i = 0; i < 4; ++i) { nacc[0][i] = z4; nacc[1][i] = z4; }
    if (wq < 3) {
        const __bf16* nbase = ts2T + (size_t)(wq * 4) * 6 * 512 + foff;
        bf16x8 bcur[4];
#pragma unroll
        for (int i = 0; i < 4; ++i) bcur[i] = *(const bf16x8*)(nbase + i * 3072);
#pragma unroll 1
        for (int ks = 0; ks < 6; ++ks) {
            bf16x8 bnext[4];
            if (ks < 5) {
#pragma unroll
                for (int i = 0; i < 4; ++i)
                    bnext[i] = *(const bf16x8*)(nbase + i * 3072 + (ks + 1) * 512);
            }
            __builtin_amdgcn_sched_barrier(0);
            bf16x8 af0 = *(const bf16x8*)(hts + lr * HTS_S + ks * 32 + lg * 8);
            bf16x8 af1 = *(const bf16x8*)(hts + (16 + lr) * HTS_S + ks * 32 + lg * 8);
#pragma unroll
            for (int i = 0; i < 4; ++i) {
                nacc[0][i] = __builtin_amdgcn_mfma_f32_16x16x32_bf16(af0, bcur[i], nacc[0][i], 0, 0, 0);
                nacc[1][i] = __builtin_amdgcn_mfma_f32_16x16x32_bf16(af1, bcur[i], nacc[1][i], 0, 0, 0);
            }
            if (ks < 5) {
#pragma unroll
                for (int i = 0; i < 4; ++i) bcur[i] = bnext[i];
            }
        }
    } else {
#pragma unroll
        for (int ks = 0; ks < 2; ++ks) {
            bf16x8 af0 = *(const bf16x8*)(haux + lr * HAUX_S + ks * 32 + lg * 8);
            bf16x8 af1 = *(const bf16x8*)(haux + (16 + lr) * HAUX_S + ks * 32 + lg * 8);
#pragma unroll
            for (int i = 0; i < 4; ++i) {
                bf16x8 bf = *(const bf16x8*)(a2T + (i * 2 + ks) * 512 + foff);
                nacc[0][i] = __builtin_amdgcn_mfma_f32_16x16x32_bf16(af0, bf, nacc[0][i], 0, 0, 0);
                nacc[1][i] = __builtin_amdgcn_mfma_f32_16x16x32_bf16(af1, bf, nacc[1][i], 0, 0, 0);
            }
        }
    }
    __syncthreads();

    // ---- phase 3c: key/val assembly
#pragma unroll
    for (int i = 0; i < 4; ++i) {
        int gcol = wq * 64 + i * 16 + lr;
        float nb_bias = (wq < 3) ? b_ts2[gcol] : b_a2[gcol - 192];
        float ed_bias = b_e2[gcol];
#pragma unroll
        for (int rf = 0; rf < 2; ++rf)
#pragma unroll
            for (int r = 0; r < 4; ++r) {
                int row = rf * 16 + crow0 + r;
                float p = pe[(t0 + row) * D_ + gcol];
                float nb = nacc[rf][i][r] + nb_bias;
                float ed = eacc[rf][i][r] + ed_bias;
                skey[row * SK_S + gcol] = (__bf16)(nb * ed + p);
                sval[row * SK_S + gcol] = (__bf16)(nb + p);
            }
    }
    __syncthreads();

    size_t key0 = (size_t)n * T_ + t0;

    // ---- phase 4 (FUSED K+V projection): one ks loop, 16 MFMAs per B-load wait.
    // No bnext prefetch (keeps VGPR <= ~72: bK+bV=32, af pairs reused, acc in AGPR).
    {
        const __bf16* kbse = WkT + (size_t)(wq * 4) * 8 * 512 + foff;
        const __bf16* vbse = WvT + (size_t)(wq * 4) * 8 * 512 + foff;
        f32x4 ka[2][4], va[2][4];
#pragma unroll
        for (int i = 0; i < 4; ++i) {
            ka[0][i] = z4; ka[1][i] = z4;
            va[0][i] = z4; va[1][i] = z4;
        }
#pragma unroll 1
        for (int ks = 0; ks < 8; ++ks) {
            bf16x8 bK[4], bV[4];
#pragma unroll
            for (int i = 0; i < 4; ++i) {
                bK[i] = *(const bf16x8*)(kbse + i * 4096 + ks * 512);
                bV[i] = *(const bf16x8*)(vbse + i * 4096 + ks * 512);
            }
            __builtin_amdgcn_sched_barrier(0);
            {
                bf16x8 af0 = *(const bf16x8*)(skey + lr * SK_S + ks * 32 + lg * 8);
                bf16x8 af1 = *(const bf16x8*)(skey + (16 + lr) * SK_S + ks * 32 + lg * 8);
#pragma unroll
                for (int i = 0; i < 4; ++i) {
                    ka[0][i] = __builtin_amdgcn_mfma_f32_16x16x32_bf16(af0, bK[i], ka[0][i], 0, 0, 0);
                    ka[1][i] = __builtin_amdgcn_mfma_f32_16x16x32_bf16(af1, bK[i], ka[1][i], 0, 0, 0);
                }
            }
            {
                bf16x8 af0 = *(const bf16x8*)(sval + lr * SK_S + ks * 32 + lg * 8);
                bf16x8 af1 = *(const bf16x8*)(sval + (16 + lr) * SK_S + ks * 32 + lg * 8);
#pragma unroll
                for (int i = 0; i < 4; ++i) {
                    va[0][i] = __builtin_amdgcn_mfma_f32_16x16x32_bf16(af0, bV[i], va[0][i], 0, 0, 0);
                    va[1][i] = __builtin_amdgcn_mfma_f32_16x16x32_bf16(af1, bV[i], va[1][i], 0, 0, 0);
                }
            }
        }

        // ---- K store
#pragma unroll
        for (int i = 0; i < 4; ++i) {
            int gcol = wq * 64 + i * 16 + lr;
            float kbias = bk[gcol];
            int h = gcol >> 5, dd = gcol & 31;
            size_t bh = (size_t)b * H_ + h;
#pragma unroll
            for (int rf = 0; rf < 2; ++rf) {
                int crow = rf * 16 + crow0;
#pragma unroll
                for (int r = 0; r < 4; ++r)
                    Kb[(bh * NT_ + key0 + crow + r) * DK_ + dd] = (__bf16)(ka[rf][i][r] + kbias);
            }
        }

        // ---- V store (fragment-tiled layout for attn)
#pragma unroll
        for (int i = 0; i < 4; ++i) {
            int gcol = wq * 64 + i * 16 + lr;
            float vbias = bv[gcol];
            int h = gcol >> 5, dd = gcol & 31;
            size_t bh = (size_t)b * H_ + h;
#pragma unroll
            for (int rf = 0; rf < 2; ++rf) {
                int crow = rf * 16 + crow0;
                __bf16 tmp[4];
#pragma unroll
                for (int r = 0; r < 4; ++r) tmp[r] = (__bf16)(va[rf][i][r] + vbias);
                size_t kg = key0 + crow;
                int within = (int)(kg & 63);
                int vks = within >> 4, vl5 = (within >> 3) & 1, j0 = within & 7;
                size_t tile = kg >> 6;
                size_t vaddr = ((bh * (NT_ / 64) + tile) * 4 + vks) * 512 +
                               (size_t)(vl5 * 32 + dd) * 8 + j0;
                *(ushort4*)(Vf + vaddr) = *(ushort4*)tmp;
            }
        }
    }
}

// ------- 32x32 MFMA attention: raw v_exp (exp2 domain), sbfe mask, ones-MFMA l
// Opart stored bf16 (unnormalized partial O; bf16 rel-err ~0.4% << threshold)
__global__ __launch_bounds__(256, 4) void attn_mfma_kernel(
    const __bf16* __restrict__ Qb, const __bf16* __restrict__ Kb,
    const __bf16* __restrict__ Vf, const ull* __restrict__ bitsT,
    __bf16* __restrict__ Opart, float* __restrict__ Lpart) {
    int blk = blockIdx.x;
    int kh = blk & (SPLIT_ - 1);
    int qt = (blk >> 3) & 3;
    int h = (blk >> 5) & 7;
    int b = blk >> 8;
    int tid = threadIdx.x, lane = tid & 63, w = tid >> 6;
    int lq = lane & 31, l5 = lane >> 5;

    const size_t bh = (size_t)b * H_ + h;
    const int TILES = KWORDS_ / SPLIT_;   // 16

    int qglob = qt * 128 + w * 32 + lq;
    const __bf16* qbase = Qb + ((size_t)b * T_ + qglob) * D_ + h * DK_ + l5 * 8;
    bf16x8 qf0 = *(const bf16x8*)(qbase);
    bf16x8 qf1 = *(const bf16x8*)(qbase + 16);

    const __bf16* kp = Kb + bh * NT_ * DK_ + (size_t)(kh * TILES) * 64 * DK_;
    const __bf16* vp = Vf + (bh * (NT_ / 64) + (size_t)(kh * TILES)) * 2048;
    const ull* mp = bitsT + (size_t)b * KWORDS_ * T_ + (size_t)(kh * TILES) * T_ + qglob;

    int k00 = lq * DK_ + l5 * 8;
    int k01 = k00 + 16;
    int k10 = (32 + lq) * DK_ + l5 * 8;
    int k11 = k10 + 16;
    int shamt = 4 * l5;

    f32x16 acc, acc_l, zv;
#pragma unroll
    for (int i = 0; i < 16; ++i) { acc[i] = 0.f; acc_l[i] = 0.f; zv[i] = 0.f; }
    union { uint u[4]; bf16x8 v; } onesf;
    onesf.u[0] = 0x3F803F80u; onesf.u[1] = 0x3F803F80u;
    onesf.u[2] = 0x3F803F80u; onesf.u[3] = 0x3F803F80u;

    bf16x8 kc0 = *(const bf16x8*)(kp + k00);
    bf16x8 kc1 = *(const bf16x8*)(kp + k01);
    bf16x8 kc2 = *(const bf16x8*)(kp + k10);
    bf16x8 kc3 = *(const bf16x8*)(kp + k11);
    ull mw = *mp;

#pragma unroll 1
    for (int kt = 0; kt < TILES; ++kt) {
        bf16x8 vc0 = *(const bf16x8*)(vp + 0 * 512 + lane * 8);
        bf16x8 vc1 = *(const bf16x8*)(vp + 1 * 512 + lane * 8);
        bf16x8 vc2 = *(const bf16x8*)(vp + 2 * 512 + lane * 8);
        bf16x8 vc3 = *(const bf16x8*)(vp + 3 * 512 + lane * 8);
        bf16x8 kn0, kn1, kn2, kn3;
        ull mn = 0;
        if (kt + 1 < TILES) {
            kn0 = *(const bf16x8*)(kp + 2048 + k00);
            kn1 = *(const bf16x8*)(kp + 2048 + k01);
            kn2 = *(const bf16x8*)(kp + 2048 + k10);
            kn3 = *(const bf16x8*)(kp + 2048 + k11);
            mn = mp[T_];
        }
        __builtin_amdgcn_sched_barrier(0);

        ull sh = mw >> shamt;

#pragma unroll
        for (int s = 0; s < 2; ++s) {
            f32x16 sc = __builtin_amdgcn_mfma_f32_32x32x16_bf16(
                s ? kc2 : kc0, qf0, zv, 0, 0, 0);
            sc = __builtin_amdgcn_mfma_f32_32x32x16_bf16(
                s ? kc3 : kc1, qf1, sc, 0, 0, 0);

            uint ms = (uint)(sh >> (32 * s));
            float p[16];
#pragma unroll
            for (int r = 0; r < 16; ++r) {
                int pos = (r & 3) + 8 * (r >> 2);
                float e = __builtin_amdgcn_exp2f(sc[r]);                 // raw v_exp
                int mb = __builtin_amdgcn_sbfe((int)ms, (uint)pos, 1u);  // 0 or -1
                p[r] = __uint_as_float(__float_as_uint(e) & (uint)mb);
            }

#pragma unroll
            for (int h2 = 0; h2 < 2; ++h2) {
                uint w0, w1, w2, w3;
                asm("v_cvt_pk_bf16_f32 %0, %1, %2" : "=v"(w0) : "v"(p[8 * h2 + 0]), "v"(p[8 * h2 + 1]));
                asm("v_cvt_pk_bf16_f32 %0, %1, %2" : "=v"(w1) : "v"(p[8 * h2 + 2]), "v"(p[8 * h2 + 3]));
                asm("v_cvt_pk_bf16_f32 %0, %1, %2" : "=v"(w2) : "v"(p[8 * h2 + 4]), "v"(p[8 * h2 + 5]));
                asm("v_cvt_pk_bf16_f32 %0, %1, %2" : "=v"(w3) : "v"(p[8 * h2 + 6]), "v"(p[8 * h2 + 7]));
                asm volatile("v_permlane32_swap_b32 %0, %1" : "+v"(w0), "+v"(w2));
                asm volatile("v_permlane32_swap_b32 %0, %1" : "+v"(w1), "+v"(w3));
                union { uint u[4]; bf16x8 v; } pa;
                pa.u[0] = w0; pa.u[1] = w1; pa.u[2] = w2; pa.u[3] = w3;
                bf16x8 vfr = (s == 0) ? (h2 == 0 ? vc0 : vc1) : (h2 == 0 ? vc2 : vc3);
                acc = __builtin_amdgcn_mfma_f32_32x32x16_bf16(pa.v, vfr, acc, 0, 0, 0);
                acc_l = __builtin_amdgcn_mfma_f32_32x32x16_bf16(pa.v, onesf.v, acc_l, 0, 0, 0);
            }
        }

        kp += 2048;
        vp += 2048;
        mp += T_;
        if (kt + 1 < TILES) {
            kc0 = kn0; kc1 = kn1; kc2 = kn2; kc3 = kn3;
            mw = mn;
        }
    }

    size_t obase = (((size_t)kh * B_ + b) * H_ + h) * T_ + qt * 128 + w * 32;
#pragma unroll
    for (int r = 0; r < 16; ++r) {
        int q = (r & 3) + 8 * (r >> 2) + 4 * l5;
        Opart[(obase + q) * DK_ + lq] = (__bf16)acc[r];
    }
    if (lq == 0) {
#pragma unroll
        for (int r = 0; r < 16; ++r) {
            int q = (r & 3) + 8 * (r >> 2) + 4 * l5;
            Lpart[obase + q] = acc_l[r];
        }
    }
}

// ------ out = (x+pe) + (merge of bf16 Opart / f32 Lpart)@Wo + bo, grid 64
__global__ __launch_bounds__(256) void out_mfma_kernel(
    const __bf16* __restrict__ Opart, const float* __restrict__ Lpart,
    const float* __restrict__ x, const float* __restrict__ pe,
    const __bf16* __restrict__ WoT, const float* __restrict__ bo,
    float* __restrict__ out) {
    int blk = blockIdx.x;
    int t0 = (blk & 15) * 32;
    int b = blk >> 4;
    int tid = threadIdx.x, lane = tid & 63;
    int wq = tid >> 6, lr = lane & 15, lg = lane >> 4;

    __shared__ __bf16 sc_[32 * SK_S];
    __shared__ float sLinv[32 * 8];
    size_t ps = (size_t)B_ * H_ * T_;

    // phase A: 1/L per (row, head)
    {
        int row = tid >> 3, hh = tid & 7;
        size_t base = ((size_t)b * H_ + hh) * T_ + t0 + row;
        float L = 0.f;
#pragma unroll
        for (int s = 0; s < SPLIT_; ++s) L += Lpart[s * ps + base];
        sLinv[row * 8 + hh] = 1.0f / L;
    }
    __syncthreads();

    // phase B: merge bf16 Opart -> ctx bf16 in LDS
    for (int idx = tid; idx < 32 * 64; idx += 256) {
        int r = idx >> 6, g = idx & 63;
        int hh = g >> 3, d4 = (g & 7) * 4;
        size_t base = (((size_t)b * H_ + hh) * T_ + t0 + r) * DK_ + d4;
        float o0 = 0.f, o1 = 0.f, o2 = 0.f, o3 = 0.f;
#pragma unroll
        for (int s = 0; s < SPLIT_; ++s) {
            union { ushort4 u; __bf16 h[4]; } cv;
            cv.u = *(const ushort4*)(Opart + s * ps * DK_ + base);
            o0 += (float)cv.h[0]; o1 += (float)cv.h[1];
            o2 += (float)cv.h[2]; o3 += (float)cv.h[3];
        }
        float li = sLinv[r * 8 + hh];
        int c = hh * 32 + d4;
        sc_[r * SK_S + c + 0] = (__bf16)(o0 * li);
        sc_[r * SK_S + c + 1] = (__bf16)(o1 * li);
        sc_[r * SK_S + c + 2] = (__bf16)(o2 * li);
        sc_[r * SK_S + c + 3] = (__bf16)(o3 * li);
    }
    __syncthreads();

    int foff = lr * 32 + lg * 8;
    int crow0 = lg * 4;
    f32x4 z4 = {0.f, 0.f, 0.f, 0.f};
    f32x4 oa[2][4];
#pragma unroll
    for (int i = 0; i < 4; ++i) { oa[0][i] = z4; oa[1][i] = z4; }
    const __bf16* obse = WoT + (size_t)(wq * 4) * 8 * 512 + foff;
#pragma unroll
    for (int ks = 0; ks < 8; ++ks) {
        bf16x8 af0 = *(const bf16x8*)(sc_ + lr * SK_S + ks * 32 + lg * 8);
        bf16x8 af1 = *(const bf16x8*)(sc_ + (16 + lr) * SK_S + ks * 32 + lg * 8);
#pragma unroll
        for (int i = 0; i < 4; ++i) {
            bf16x8 b8 = *(const bf16x8*)(obse + i * 4096 + ks * 512);
            oa[0][i] = __builtin_amdgcn_mfma_f32_16x16x32_bf16(af0, b8, oa[0][i], 0, 0, 0);
            oa[1][i] = __builtin_amdgcn_mfma_f32_16x16x32_bf16(af1, b8, oa[1][i], 0, 0, 0);
        }
    }
#pragma unroll
    for (int i = 0; i < 4; ++i) {
        int gcol = wq * 64 + i * 16 + lr;
        float bias = bo[gcol];
#pragma unroll
        for (int rf = 0; rf < 2; ++rf)
#pragma unroll
            for (int r = 0; r < 4; ++r) {
                int t = t0 + rf * 16 + crow0 + r;
                size_t off = ((size_t)b * T_ + t) * D_ + gcol;
                out[off] = x[off] + pe[t * D_ + gcol] + oa[rf][i][r] + bias;
            }
    }
}

// ---------------------------------------------------------------- launcher
extern "C" void kernel_launch(void* const* d_in, const int* in_sizes, int n_in,
                              void* d_out, int out_size, void* d_ws, size_t ws_size,
                              hipStream_t stream) {
    const float* x = (const float*)d_in[0];
    const float* md = (const float*)d_in[1];
    const float* na = (const float*)d_in[2];
    const float* ea = (const float*)d_in[3];
    const int* mask = (const int*)d_in[4];
    const float* W_ts1 = (const float*)d_in[5];
    const float* b_ts1 = (const float*)d_in[6];
    const float* W_ts2 = (const float*)d_in[7];
    const float* b_ts2 = (const float*)d_in[8];
    const float* W_a1 = (const float*)d_in[9];
    const float* b_a1 = (const float*)d_in[10];
    const float* W_a2 = (const float*)d_in[11];
    const float* b_a2 = (const float*)d_in[12];
    const float* W_e1 = (const float*)d_in[13];
    const float* b_e1 = (const float*)d_in[14];
    const float* W_e2 = (const float*)d_in[15];
    const float* b_e2 = (const float*)d_in[16];
    const float* Wq = (const float*)d_in[17];
    const float* bq = (const float*)d_in[18];
    const float* Wk = (const float*)d_in[19];
    const float* bk = (const float*)d_in[20];
    const float* Wv = (const float*)d_in[21];
    const float* bv = (const float*)d_in[22];
    const float* Wo = (const float*)d_in[23];
    const float* bo = (const float*)d_in[24];
    const float* ln_g = (const float*)d_in[25];
    const float* ln_b = (const float*)d_in[26];
    float* out = (float*)d_out;

    char* ws = (char*)d_ws;
    float* pe = (float*)ws;      ws += (size_t)T_ * D_ * 4;
    ull* bitsT = (ull*)ws;       ws += (size_t)B_ * KWORDS_ * T_ * 8;    // 2 MB
    __bf16* Kb = (__bf16*)ws;    ws += (size_t)B_ * H_ * NT_ * DK_ * 2;  // 16 MB
    __bf16* Vf = (__bf16*)ws;    ws += (size_t)B_ * H_ * NT_ * DK_ * 2;  // 16 MB
    __bf16* Qb = (__bf16*)ws;    ws += (size_t)B_ * T_ * D_ * 2;         // 1 MB
    __bf16* Opart = (__bf16*)ws; ws += (size_t)SPLIT_ * B_ * H_ * T_ * DK_ * 2;  // 8 MB
    float* Lpart = (float*)ws;   ws += (size_t)SPLIT_ * B_ * H_ * T_ * 4;
    // bf16 prepped weights
    __bf16* ts1P = (__bf16*)ws; ws += 6144 * 2;
    __bf16* a1P = (__bf16*)ws;  ws += 2048 * 2;
    __bf16* e1P = (__bf16*)ws;  ws += 8192 * 2;
    __bf16* ts2T = (__bf16*)ws; ws += 36864 * 2;
    __bf16* a2T = (__bf16*)ws;  ws += 4096 * 2;
    __bf16* e2T = (__bf16*)ws;  ws += 65536 * 2;
    __bf16* WkT = (__bf16*)ws;  ws += 65536 * 2;
    __bf16* WvT = (__bf16*)ws;  ws += 65536 * 2;
    __bf16* WqT = (__bf16*)ws;  ws += 65536 * 2;
    __bf16* WoT = (__bf16*)ws;  ws += 65536 * 2;

    prep_kernel<<<4064, 256, 0, stream>>>(mask, bitsT, pe,
                                          W_ts1, W_a1, W_e1, W_ts2, W_a2, W_e2,
                                          Wk, Wv, Wq, Wo,
                                          ts1P, a1P, e1P, ts2T, a2T, e2T,
                                          WkT, WvT, WqT, WoT);
    kvq_mfma_kernel<<<B_ * N_ * (T_ / 32) + B_ * (T_ / 32), 256, 0, stream>>>(
        md, na, ea, ts1P, a1P, e1P, b_ts1, b_a1, b_e1,
        ts2T, a2T, e2T, b_ts2, b_a2, b_e2, WkT, bk, WvT, bv, pe, Kb, Vf,
        x, WqT, bq, ln_g, ln_b, Qb);
    attn_mfma_kernel<<<B_ * H_ * (T_ / 128) * SPLIT_, 256, 0, stream>>>(
        Qb, Kb, Vf, bitsT, Opart, Lpart);
    out_mfma_kernel<<<B_ * (T_ / 32), 256, 0, stream>>>(Opart, Lpart, x, pe, WoT, bo, out);
}